// Round 2
// baseline (724.842 us; speedup 1.0000x reference)
//
#include <hip/hip_runtime.h>
#include <cstddef>

#define N_NODES 10000
#define N_EDGES 160000
#define E_TOT   170000
#define N_GRAPHS 64
#define NF 64
#define HID 128
#define HC 512
#define NHEAD 4
#define LAT 64
#define MAXN 50
#define NPAIR 1225
#define NODESF 3200
#define NROWS_ER 78400   // 64*1225

// ---------------- blocked dense: out = act(in @ W + b) ----------------
// 16 rows per block (rows must be multiple of 16), 256 threads.
// JC cols per block-col (grid.y = Nout/JC), RPG rows per thread.
// ACT: 0 none, 1 relu, 2 sigmoid
template<int ACT, int RPG, int JC>
__global__ void bdense_kernel(const float* __restrict__ in, const float* __restrict__ W,
                              const float* __restrict__ bias, float* __restrict__ out,
                              int K, int logK, int Nout) {
    extern __shared__ float inL[];   // 16 * K floats
    int t = threadIdx.x;
    int row0 = blockIdx.x * 16;
    int j0 = blockIdx.y * JC;
    for (int idx = t; idx < 16 * K; idx += 256) {
        int r = idx >> logK, c = idx & (K - 1);
        inL[idx] = in[(size_t)(row0 + r) * K + c];
    }
    __syncthreads();
    int j = j0 + (t & (JC - 1));
    int rr = (t / JC) * RPG;
    float acc[RPG];
    float bj = bias ? bias[j] : 0.f;
#pragma unroll
    for (int r = 0; r < RPG; ++r) acc[r] = bj;
    for (int k = 0; k < K; k += 4) {
        float w0 = W[(size_t)k * Nout + j];
        float w1 = W[(size_t)(k + 1) * Nout + j];
        float w2 = W[(size_t)(k + 2) * Nout + j];
        float w3 = W[(size_t)(k + 3) * Nout + j];
#pragma unroll
        for (int r = 0; r < RPG; ++r) {
            const float4 v = *(const float4*)&inL[((rr + r) << logK) + k];
            acc[r] = fmaf(v.x, w0, acc[r]);
            acc[r] = fmaf(v.y, w1, acc[r]);
            acc[r] = fmaf(v.z, w2, acc[r]);
            acc[r] = fmaf(v.w, w3, acc[r]);
        }
    }
#pragma unroll
    for (int r = 0; r < RPG; ++r) {
        float v = acc[r];
        if (ACT == 1) v = fmaxf(v, 0.f);
        else if (ACT == 2) v = 1.f / (1.f + __expf(-v));
        out[(size_t)(row0 + rr + r) * Nout + j] = v;
    }
}

// ---------------- CSR build ----------------
__global__ void deg_kernel(const int* __restrict__ ei, int* __restrict__ deg) {
    int e = blockIdx.x * blockDim.x + threadIdx.x;
    if (e >= E_TOT) return;
    int d = (e < N_EDGES) ? ei[N_EDGES + e] : (e - N_EDGES);
    atomicAdd(&deg[d], 1);
}

__global__ void scan_kernel(const int* __restrict__ deg, int* __restrict__ rowstart) {
    __shared__ int lds[1024];
    __shared__ int carry;
    if (threadIdx.x == 0) carry = 0;
    __syncthreads();
    for (int base = 0; base < N_NODES; base += 1024) {
        int i = base + (int)threadIdx.x;
        int v = (i < N_NODES) ? deg[i] : 0;
        lds[threadIdx.x] = v;
        __syncthreads();
        for (int off = 1; off < 1024; off <<= 1) {
            int tv = (threadIdx.x >= (unsigned)off) ? lds[threadIdx.x - off] : 0;
            __syncthreads();
            lds[threadIdx.x] += tv;
            __syncthreads();
        }
        int incl = lds[threadIdx.x];
        if (i < N_NODES) rowstart[i] = carry + incl - v;
        __syncthreads();
        if (threadIdx.x == 1023) carry += lds[1023];
        __syncthreads();
    }
    if (threadIdx.x == 0) rowstart[N_NODES] = carry;
}

__global__ void fill_kernel(const int* __restrict__ ei, const int* __restrict__ rowstart,
                            int* __restrict__ cursor, int* __restrict__ csr_src) {
    int e = blockIdx.x * blockDim.x + threadIdx.x;
    if (e >= E_TOT) return;
    int s, d;
    if (e < N_EDGES) { s = ei[e]; d = ei[N_EDGES + e]; }
    else { s = e - N_EDGES; d = s; }
    int pos = atomicAdd(&cursor[d], 1);
    csr_src[rowstart[d] + pos] = s;
}

// ---------------- es/ed: per-head dot of xh row with attention vectors ----------------
__global__ void esed_kernel(const float* __restrict__ xh, const float* __restrict__ ags,
                            const float* __restrict__ agd, float* __restrict__ es,
                            float* __restrict__ ed) {
    int wave = threadIdx.x >> 6, lane = threadIdx.x & 63;
    int n = blockIdx.x * 4 + wave;
    if (n >= N_NODES) return;
    const float* row = xh + (size_t)n * HC;
    float ps[4] = {0.f, 0.f, 0.f, 0.f}, pd[4] = {0.f, 0.f, 0.f, 0.f};
#pragma unroll
    for (int m = 0; m < 8; ++m) {
        int idx = m * 64 + lane;
        int h = m >> 1;
        float v = row[idx];
        ps[h] = fmaf(v, ags[idx], ps[h]);
        pd[h] = fmaf(v, agd[idx], pd[h]);
    }
#pragma unroll
    for (int h = 0; h < 4; ++h) {
        float a = ps[h], d = pd[h];
        for (int off = 32; off; off >>= 1) { a += __shfl_xor(a, off); d += __shfl_xor(d, off); }
        if (lane == 0) { es[n * 4 + h] = a; ed[n * 4 + h] = d; }
    }
}

// ---------------- GAT aggregation: one wave per dst node ----------------
__global__ void gat_agg_kernel(const float* __restrict__ xh, const float* __restrict__ es,
                               const float* __restrict__ ed, const int* __restrict__ rowstart,
                               const int* __restrict__ csr_src, const float* __restrict__ bg,
                               float* __restrict__ h) {
    __shared__ float aL[64][4];
    __shared__ int sL[64];
    int n = blockIdx.x;
    int lane = threadIdx.x;
    int r0 = rowstart[n], r1 = rowstart[n + 1];
    int deg = r1 - r0;
    const float4 ed4 = ((const float4*)ed)[n];
    const float edh[4] = {ed4.x, ed4.y, ed4.z, ed4.w};
    // pass A: per-head max
    float mx[4] = {-3.4e38f, -3.4e38f, -3.4e38f, -3.4e38f};
    for (int j = lane; j < deg; j += 64) {
        int s = csr_src[r0 + j];
        const float4 e4 = ((const float4*)es)[s];
        const float ev[4] = {e4.x, e4.y, e4.z, e4.w};
#pragma unroll
        for (int hh = 0; hh < 4; ++hh) {
            float e = ev[hh] + edh[hh];
            e = e > 0.f ? e : 0.2f * e;
            mx[hh] = fmaxf(mx[hh], e);
        }
    }
#pragma unroll
    for (int hh = 0; hh < 4; ++hh)
        for (int off = 32; off; off >>= 1) mx[hh] = fmaxf(mx[hh], __shfl_xor(mx[hh], off));
    // pass B: denominator
    float den[4] = {0.f, 0.f, 0.f, 0.f};
    for (int j = lane; j < deg; j += 64) {
        int s = csr_src[r0 + j];
        const float4 e4 = ((const float4*)es)[s];
        const float ev[4] = {e4.x, e4.y, e4.z, e4.w};
#pragma unroll
        for (int hh = 0; hh < 4; ++hh) {
            float e = ev[hh] + edh[hh];
            e = e > 0.f ? e : 0.2f * e;
            den[hh] += __expf(e - mx[hh]);
        }
    }
#pragma unroll
    for (int hh = 0; hh < 4; ++hh) {
        for (int off = 32; off; off >>= 1) den[hh] += __shfl_xor(den[hh], off);
        den[hh] = 1.f / den[hh];
    }
    // pass C: weighted accumulate, chunks of 64 edges
    float acc[8] = {0.f, 0.f, 0.f, 0.f, 0.f, 0.f, 0.f, 0.f};
    for (int base = 0; base < deg; base += 64) {
        int j = base + lane;
        if (j < deg) {
            int s = csr_src[r0 + j];
            sL[lane] = s;
            const float4 e4 = ((const float4*)es)[s];
            const float ev[4] = {e4.x, e4.y, e4.z, e4.w};
            float al[4];
#pragma unroll
            for (int hh = 0; hh < 4; ++hh) {
                float e = ev[hh] + edh[hh];
                e = e > 0.f ? e : 0.2f * e;
                al[hh] = __expf(e - mx[hh]) * den[hh];
            }
            *(float4*)&aL[lane][0] = make_float4(al[0], al[1], al[2], al[3]);
        }
        __syncthreads();
        int cnt = min(64, deg - base);
        for (int j2 = 0; j2 < cnt; ++j2) {
            int s = sL[j2];
            const float* xr = xh + (size_t)s * HC;
            const float4 a4 = *(const float4*)&aL[j2][0];
            const float av[4] = {a4.x, a4.y, a4.z, a4.w};
#pragma unroll
            for (int m = 0; m < 8; ++m) {
                acc[m] = fmaf(av[m >> 1], xr[m * 64 + lane], acc[m]);
            }
        }
        __syncthreads();
    }
    float o1 = (acc[0] + acc[2] + acc[4] + acc[6]) * 0.25f + bg[lane];
    float o2 = (acc[1] + acc[3] + acc[5] + acc[7]) * 0.25f + bg[64 + lane];
    o1 = fmaxf(o1, 0.f);
    o2 = fmaxf(o2, 0.f);
    h[(size_t)n * HID + lane] += o1;
    h[(size_t)n * HID + 64 + lane] += o2;
}

// ---------------- pooling ----------------
__global__ void pool_kernel(const float* __restrict__ h, const int* __restrict__ batch,
                            float* __restrict__ sums, float* __restrict__ counts) {
    int n = blockIdx.x;
    int t = threadIdx.x;
    int g = batch[n];
    atomicAdd(&sums[g * HID + t], h[(size_t)n * HID + t]);
    if (t == 0) atomicAdd(&counts[g], 1.f);
}

__global__ void prdiv_kernel(const float* __restrict__ sums, const float* __restrict__ counts,
                             float* __restrict__ pr0) {
    int g = blockIdx.x, t = threadIdx.x;
    float c = fmaxf(counts[g], 1.f);
    pr0[g * HID + t] = sums[g * HID + t] / c;
}

// ---------------- z = mu + eps * exp(0.5*logvar) ----------------
__global__ void z_kernel(const float* __restrict__ mu, const float* __restrict__ lv,
                         const float* __restrict__ eps, float* __restrict__ z) {
    int i = blockIdx.x * blockDim.x + threadIdx.x;
    if (i < N_GRAPHS * LAT) z[i] = fmaf(eps[i], __expf(0.5f * lv[i]), mu[i]);
}

__global__ void sigmoid_kernel(const float* __restrict__ in, float* __restrict__ out, int n) {
    int i = blockIdx.x * blockDim.x + threadIdx.x;
    if (i < n) out[i] = 1.f / (1.f + __expf(-in[i]));
}

// ---------------- triu pair indices ----------------
__global__ void pairs_kernel(int* __restrict__ pi, int* __restrict__ pj) {
    int p = blockIdx.x * blockDim.x + threadIdx.x;
    if (p >= NPAIR) return;
    int i = 0, off = 0;
    while (off + (MAXN - 1 - i) <= p) { off += MAXN - 1 - i; ++i; }
    pi[p] = i;
    pj[p] = i + 1 + (p - off);
}

// ---------------- fused edge + reaction MLPs, 16 rows per block ----------------
__global__ void edge_react_kernel(const float* __restrict__ z, const float* __restrict__ nodes,
                                  const int* __restrict__ pi, const int* __restrict__ pj,
                                  const float* __restrict__ We1, const float* __restrict__ be1,
                                  const float* __restrict__ We2, const float* __restrict__ be2,
                                  const float* __restrict__ We3, const float* __restrict__ be3,
                                  const float* __restrict__ Wr1, const float* __restrict__ br1,
                                  const float* __restrict__ Wr2, const float* __restrict__ br2,
                                  float* __restrict__ edge_probs, float* __restrict__ react) {
    __shared__ float inL[16][192];
    __shared__ float h1L[16][128];
    __shared__ float h2L[16][64];
    __shared__ float rhL[16][64];
    int t = threadIdx.x;
    int row0 = blockIdx.x * 16;
    for (int idx = t; idx < 16 * 192; idx += 256) {
        int r = idx / 192, c = idx - r * 192;
        int grow = row0 + r;
        int b = grow / NPAIR, p = grow - b * NPAIR;
        float v;
        if (c < 64) v = z[b * LAT + c];
        else if (c < 128) v = nodes[b * NODESF + pi[p] * NF + (c - 64)];
        else v = nodes[b * NODESF + pj[p] * NF + (c - 128)];
        inL[r][c] = v;
    }
    __syncthreads();
    // edge layer1: 192 -> 128
    {
        int j = t & 127, rr = (t >> 7) * 8;
        float acc[8];
#pragma unroll
        for (int r = 0; r < 8; ++r) acc[r] = be1[j];
        for (int k = 0; k < 192; k += 4) {
            float w0 = We1[(k + 0) * 128 + j];
            float w1 = We1[(k + 1) * 128 + j];
            float w2 = We1[(k + 2) * 128 + j];
            float w3 = We1[(k + 3) * 128 + j];
#pragma unroll
            for (int r = 0; r < 8; ++r) {
                const float4 v = *(const float4*)&inL[rr + r][k];
                acc[r] = fmaf(v.x, w0, acc[r]);
                acc[r] = fmaf(v.y, w1, acc[r]);
                acc[r] = fmaf(v.z, w2, acc[r]);
                acc[r] = fmaf(v.w, w3, acc[r]);
            }
        }
#pragma unroll
        for (int r = 0; r < 8; ++r) h1L[rr + r][j] = fmaxf(acc[r], 0.f);
    }
    // reaction layer1: 128 -> 64 (input = inL[.][64..191])
    {
        int j = t & 63, rr = (t >> 6) * 4;
        float acc[4];
#pragma unroll
        for (int r = 0; r < 4; ++r) acc[r] = br1[j];
        for (int k = 0; k < 128; k += 4) {
            float w0 = Wr1[(k + 0) * 64 + j];
            float w1 = Wr1[(k + 1) * 64 + j];
            float w2 = Wr1[(k + 2) * 64 + j];
            float w3 = Wr1[(k + 3) * 64 + j];
#pragma unroll
            for (int r = 0; r < 4; ++r) {
                const float4 v = *(const float4*)&inL[rr + r][64 + k];
                acc[r] = fmaf(v.x, w0, acc[r]);
                acc[r] = fmaf(v.y, w1, acc[r]);
                acc[r] = fmaf(v.z, w2, acc[r]);
                acc[r] = fmaf(v.w, w3, acc[r]);
            }
        }
#pragma unroll
        for (int r = 0; r < 4; ++r) rhL[rr + r][j] = fmaxf(acc[r], 0.f);
    }
    __syncthreads();
    // edge layer2: 128 -> 64
    {
        int j = t & 63, rr = (t >> 6) * 4;
        float acc[4];
#pragma unroll
        for (int r = 0; r < 4; ++r) acc[r] = be2[j];
        for (int k = 0; k < 128; k += 4) {
            float w0 = We2[(k + 0) * 64 + j];
            float w1 = We2[(k + 1) * 64 + j];
            float w2 = We2[(k + 2) * 64 + j];
            float w3 = We2[(k + 3) * 64 + j];
#pragma unroll
            for (int r = 0; r < 4; ++r) {
                const float4 v = *(const float4*)&h1L[rr + r][k];
                acc[r] = fmaf(v.x, w0, acc[r]);
                acc[r] = fmaf(v.y, w1, acc[r]);
                acc[r] = fmaf(v.z, w2, acc[r]);
                acc[r] = fmaf(v.w, w3, acc[r]);
            }
        }
#pragma unroll
        for (int r = 0; r < 4; ++r) h2L[rr + r][j] = fmaxf(acc[r], 0.f);
    }
    __syncthreads();
    // edge layer3: 64 -> 1, sigmoid
    {
        int r = t >> 4, sub = t & 15;
        float p4 = 0.f;
#pragma unroll
        for (int kk = 0; kk < 4; ++kk) {
            int k = sub + kk * 16;
            p4 = fmaf(h2L[r][k], We3[k], p4);
        }
#pragma unroll
        for (int off = 8; off; off >>= 1) p4 += __shfl_xor(p4, off);
        if (sub == 0) edge_probs[row0 + r] = 1.f / (1.f + __expf(-(p4 + be3[0])));
    }
    // reaction layer2: 64 -> 6, softmax
    {
        int r = t >> 4, sub = t & 15;
        float lg[6];
#pragma unroll
        for (int m = 0; m < 6; ++m) lg[m] = 0.f;
#pragma unroll
        for (int kk = 0; kk < 4; ++kk) {
            int k = sub + kk * 16;
            float v = rhL[r][k];
#pragma unroll
            for (int m = 0; m < 6; ++m) lg[m] = fmaf(v, Wr2[k * 6 + m], lg[m]);
        }
#pragma unroll
        for (int off = 8; off; off >>= 1) {
#pragma unroll
            for (int m = 0; m < 6; ++m) lg[m] += __shfl_xor(lg[m], off);
        }
        if (sub == 0) {
            float mx = -3.4e38f;
#pragma unroll
            for (int m = 0; m < 6; ++m) { lg[m] += br2[m]; mx = fmaxf(mx, lg[m]); }
            float s = 0.f;
            float ex[6];
#pragma unroll
            for (int m = 0; m < 6; ++m) { ex[m] = __expf(lg[m] - mx); s += ex[m]; }
            float rs = 1.f / s;
#pragma unroll
            for (int m = 0; m < 6; ++m) react[(size_t)(row0 + r) * 6 + m] = ex[m] * rs;
        }
    }
}

// ---------------- launch ----------------
extern "C" void kernel_launch(void* const* d_in, const int* in_sizes, int n_in,
                              void* d_out, int out_size, void* d_ws, size_t ws_size,
                              hipStream_t stream) {
    const float* x     = (const float*)d_in[0];
    const int*   ei    = (const int*)d_in[1];
    const int*   batch = (const int*)d_in[2];
    const float* eps   = (const float*)d_in[3];
    const float* We    = (const float*)d_in[4];
    const float* be    = (const float*)d_in[5];
    const float* Wg    = (const float*)d_in[6];
    const float* ags   = (const float*)d_in[7];
    const float* agd   = (const float*)d_in[8];
    const float* bg    = (const float*)d_in[9];
    const float* Wa1   = (const float*)d_in[10];
    const float* ba1   = (const float*)d_in[11];
    const float* Wa2   = (const float*)d_in[12];
    const float* ba2   = (const float*)d_in[13];
    const float* Wmu   = (const float*)d_in[14];
    const float* bmu   = (const float*)d_in[15];
    const float* Wlv   = (const float*)d_in[16];
    const float* blv   = (const float*)d_in[17];
    const float* Wn1   = (const float*)d_in[18];
    const float* bn1   = (const float*)d_in[19];
    const float* Wn2   = (const float*)d_in[20];
    const float* bn2   = (const float*)d_in[21];
    const float* Wn3   = (const float*)d_in[22];
    const float* bn3   = (const float*)d_in[23];
    const float* We1   = (const float*)d_in[24];
    const float* be1   = (const float*)d_in[25];
    const float* We2   = (const float*)d_in[26];
    const float* be2   = (const float*)d_in[27];
    const float* We3   = (const float*)d_in[28];
    const float* be3   = (const float*)d_in[29];
    const float* Wr1   = (const float*)d_in[30];
    const float* br1   = (const float*)d_in[31];
    const float* Wr2   = (const float*)d_in[32];
    const float* br2   = (const float*)d_in[33];

    float* out = (float*)d_out;
    float* mu_o    = out;                 // 64*64
    float* lv_o    = out + 4096;          // 64*64
    float* z_o     = out + 8192;          // 64*64
    float* pr_o    = out + 12288;         // 64*128
    float* nodep_o = out + 20480;         // 64*50*64
    float* edgep_o = out + 225280;        // 64*1225
    float* react_o = out + 303680;        // 64*1225*6

    float* F = (float*)d_ws;
    size_t o = 0;
    float* h      = F + o; o += (size_t)N_NODES * HID;   // 1,280,000
    float* xh     = F + o; o += (size_t)N_NODES * HC;    // 5,120,000
    float* es     = F + o; o += (size_t)N_NODES * 4;
    float* ed     = F + o; o += (size_t)N_NODES * 4;
    float* t1     = F + o; o += 64 * 256;
    float* g1b    = F + o; o += 64 * 256;
    float* g2b    = F + o; o += 64 * 512;
    float* nodesb = F + o; o += 64 * NODESF;
    float* pr0    = F + o; o += 64 * HID;
    int* I = (int*)(F + o);
    int* rowstart = I;                  // N_NODES+1
    int* csr_src  = I + (N_NODES + 1);  // E_TOT
    int* piA      = I + (N_NODES + 1) + E_TOT;
    int* pjA      = piA + NPAIR;
    int* deg      = pjA + NPAIR;        // N_NODES  -- zeroed region starts here
    int* cursor   = deg + N_NODES;      // N_NODES
    float* sums   = (float*)(cursor + N_NODES); // 64*128
    float* counts = sums + 64 * HID;            // 64

    // zero accumulators (deg, cursor, sums, counts are contiguous)
    size_t zero_bytes = ((size_t)N_NODES * 2 + 64 * HID + 64) * 4;
    hipMemsetAsync(deg, 0, zero_bytes, stream);

    // pair indices + CSR
    pairs_kernel<<<5, 256, 0, stream>>>(piA, pjA);
    deg_kernel<<<(E_TOT + 255) / 256, 256, 0, stream>>>(ei, deg);
    scan_kernel<<<1, 1024, 0, stream>>>(deg, rowstart);
    fill_kernel<<<(E_TOT + 255) / 256, 256, 0, stream>>>(ei, rowstart, cursor, csr_src);

    // h = relu(x @ We + be)
    bdense_kernel<1, 8, 128><<<dim3(N_NODES / 16, 1), 256, 16 * 64 * 4, stream>>>(
        x, We, be, h, 64, 6, 128);

    // 3 GAT layers
    for (int l = 0; l < 3; ++l) {
        bdense_kernel<0, 8, 128><<<dim3(N_NODES / 16, 4), 256, 16 * 128 * 4, stream>>>(
            h, Wg + (size_t)l * HID * HC, nullptr, xh, 128, 7, 512);
        esed_kernel<<<N_NODES / 4, 256, 0, stream>>>(xh, ags + l * HC, agd + l * HC, es, ed);
        gat_agg_kernel<<<N_NODES, 64, 0, stream>>>(xh, es, ed, rowstart, csr_src,
                                                   bg + l * HID, h);
    }

    // pooling -> pr
    pool_kernel<<<N_NODES, 128, 0, stream>>>(h, batch, sums, counts);
    prdiv_kernel<<<64, 128, 0, stream>>>(sums, counts, pr0);
    bdense_kernel<1, 8, 128><<<dim3(4, 2), 256, 16 * 128 * 4, stream>>>(pr0, Wa1, ba1, t1, 128, 7, 256);
    bdense_kernel<0, 8, 128><<<dim3(4, 1), 256, 16 * 256 * 4, stream>>>(t1, Wa2, ba2, pr_o, 256, 8, 128);
    bdense_kernel<0, 4, 64><<<dim3(4, 1), 256, 16 * 128 * 4, stream>>>(pr_o, Wmu, bmu, mu_o, 128, 7, 64);
    bdense_kernel<0, 4, 64><<<dim3(4, 1), 256, 16 * 128 * 4, stream>>>(pr_o, Wlv, blv, lv_o, 128, 7, 64);
    z_kernel<<<16, 256, 0, stream>>>(mu_o, lv_o, eps, z_o);

    // decoder
    bdense_kernel<1, 8, 128><<<dim3(4, 2), 256, 16 * 64 * 4, stream>>>(z_o, Wn1, bn1, g1b, 64, 6, 256);
    bdense_kernel<1, 8, 128><<<dim3(4, 4), 256, 16 * 256 * 4, stream>>>(g1b, Wn2, bn2, g2b, 256, 8, 512);
    bdense_kernel<0, 8, 128><<<dim3(4, 25), 256, 16 * 512 * 4, stream>>>(g2b, Wn3, bn3, nodesb, 512, 9, 3200);
    sigmoid_kernel<<<(64 * NODESF) / 256, 256, 0, stream>>>(nodesb, nodep_o, 64 * NODESF);

    // fused edge + reaction MLPs
    edge_react_kernel<<<NROWS_ER / 16, 256, 0, stream>>>(
        z_o, nodesb, piA, pjA, We1, be1, We2, be2, We3, be3,
        Wr1, br1, Wr2, br2, edgep_o, react_o);
}

// Round 3
// 421.814 us; speedup vs baseline: 1.7184x; 1.7184x over previous
//
#include <hip/hip_runtime.h>
#include <cstddef>

#define N_NODES 10000
#define N_EDGES 160000
#define E_TOT   170000
#define N_GRAPHS 64
#define NF 64
#define HID 128
#define HC 512
#define LAT 64
#define MAXN 50
#define NPAIR 1225
#define NODESF 3200

typedef __attribute__((ext_vector_type(8))) short bf16x8;
typedef __attribute__((ext_vector_type(8))) unsigned short u16x8;
typedef __attribute__((ext_vector_type(4))) float f32x4;
typedef unsigned short u16;
typedef unsigned int u32;

__device__ __forceinline__ u16 f2b(float f) {
    u32 u = __float_as_uint(f);
    u32 r = (u + 0x7fffu + ((u >> 16) & 1u)) >> 16;
    return (u16)r;
}
__device__ __forceinline__ float b2f(u16 v) {
    return __uint_as_float(((u32)v) << 16);
}

// ---------------- blocked dense (f32, for small GEMMs): out = act(in @ W + b) ----------------
template<int ACT, int RPG, int JC>
__global__ void bdense_kernel(const float* __restrict__ in, const float* __restrict__ W,
                              const float* __restrict__ bias, float* __restrict__ out,
                              int K, int logK, int Nout) {
    extern __shared__ float inL[];
    int t = threadIdx.x;
    int row0 = blockIdx.x * 16;
    int j0 = blockIdx.y * JC;
    for (int idx = t; idx < 16 * K; idx += 256) {
        int r = idx >> logK, c = idx & (K - 1);
        inL[idx] = in[(size_t)(row0 + r) * K + c];
    }
    __syncthreads();
    int j = j0 + (t & (JC - 1));
    int rr = (t / JC) * RPG;
    float acc[RPG];
    float bj = bias ? bias[j] : 0.f;
#pragma unroll
    for (int r = 0; r < RPG; ++r) acc[r] = bj;
    for (int k = 0; k < K; k += 4) {
        float w0 = W[(size_t)k * Nout + j];
        float w1 = W[(size_t)(k + 1) * Nout + j];
        float w2 = W[(size_t)(k + 2) * Nout + j];
        float w3 = W[(size_t)(k + 3) * Nout + j];
#pragma unroll
        for (int r = 0; r < RPG; ++r) {
            const float4 v = *(const float4*)&inL[((rr + r) << logK) + k];
            acc[r] = fmaf(v.x, w0, acc[r]);
            acc[r] = fmaf(v.y, w1, acc[r]);
            acc[r] = fmaf(v.z, w2, acc[r]);
            acc[r] = fmaf(v.w, w3, acc[r]);
        }
    }
#pragma unroll
    for (int r = 0; r < RPG; ++r) {
        float v = acc[r];
        if (ACT == 1) v = fmaxf(v, 0.f);
        out[(size_t)(row0 + rr + r) * Nout + j] = v;
    }
}

// ---------------- CSR build ----------------
__global__ void deg_kernel(const int* __restrict__ ei, int* __restrict__ deg) {
    int e = blockIdx.x * blockDim.x + threadIdx.x;
    if (e >= E_TOT) return;
    int d = (e < N_EDGES) ? ei[N_EDGES + e] : (e - N_EDGES);
    atomicAdd(&deg[d], 1);
}

__global__ void scan_kernel(const int* __restrict__ deg, int* __restrict__ rowstart) {
    __shared__ int lds[1024];
    __shared__ int carry;
    if (threadIdx.x == 0) carry = 0;
    __syncthreads();
    for (int base = 0; base < N_NODES; base += 1024) {
        int i = base + (int)threadIdx.x;
        int v = (i < N_NODES) ? deg[i] : 0;
        lds[threadIdx.x] = v;
        __syncthreads();
        for (int off = 1; off < 1024; off <<= 1) {
            int tv = (threadIdx.x >= (unsigned)off) ? lds[threadIdx.x - off] : 0;
            __syncthreads();
            lds[threadIdx.x] += tv;
            __syncthreads();
        }
        int incl = lds[threadIdx.x];
        if (i < N_NODES) rowstart[i] = carry + incl - v;
        __syncthreads();
        if (threadIdx.x == 1023) carry += lds[1023];
        __syncthreads();
    }
    if (threadIdx.x == 0) rowstart[N_NODES] = carry;
}

__global__ void fill_kernel(const int* __restrict__ ei, const int* __restrict__ rowstart,
                            int* __restrict__ cursor, int* __restrict__ csr_src) {
    int e = blockIdx.x * blockDim.x + threadIdx.x;
    if (e >= E_TOT) return;
    int s, d;
    if (e < N_EDGES) { s = ei[e]; d = ei[N_EDGES + e]; }
    else { s = e - N_EDGES; d = s; }
    int pos = atomicAdd(&cursor[d], 1);
    csr_src[rowstart[d] + pos] = s;
}

// ---------------- pack W [K][N] f32 -> Bp [K/8][N][8] bf16 ----------------
__global__ void pack_b_kernel(const float* __restrict__ W, u16* __restrict__ Wp, int K8, int N) {
    int i = blockIdx.x * 256 + threadIdx.x;
    if (i >= K8 * N) return;
    int g = i / N, n = i - g * N;
    u16x8 o;
#pragma unroll
    for (int j = 0; j < 8; ++j) o[j] = f2b(W[(size_t)(g * 8 + j) * N + n]);
    *(u16x8*)&Wp[(size_t)i * 8] = o;
}

__global__ void convf2b_kernel(const float* __restrict__ src, u16* __restrict__ dst, int n) {
    int i = blockIdx.x * blockDim.x + threadIdx.x;
    if (i < n) dst[i] = f2b(src[i]);
}

// ---------------- MFMA GEMM: xh_bf16 = h_bf16 (M x128) @ Wgp (128x512) ----------------
__global__ __launch_bounds__(256) void gemm_h_kernel(const u16* __restrict__ hb,
                                                     const u16* __restrict__ Wgp,
                                                     u16* __restrict__ xhb) {
    __shared__ u16 AL[64 * 136];
    int t = threadIdx.x, w = t >> 6, l = t & 63, lr = l & 15, lg = l >> 4;
    int rb = blockIdx.x * 64, j0 = blockIdx.y * 128;
    for (int u = t; u < 1024; u += 256) {
        int r = u >> 4, q = u & 15;
        int row = min(rb + r, N_NODES - 1);
        *(u16x8*)&AL[r * 136 + q * 8] = *(const u16x8*)&hb[(size_t)row * 128 + q * 8];
    }
    __syncthreads();
    f32x4 acc[4][2];
#pragma unroll
    for (int rt = 0; rt < 4; ++rt)
#pragma unroll
        for (int ct = 0; ct < 2; ++ct) acc[rt][ct] = (f32x4){0.f, 0.f, 0.f, 0.f};
#pragma unroll
    for (int ks = 0; ks < 4; ++ks) {
        bf16x8 a[4], b[2];
#pragma unroll
        for (int rt = 0; rt < 4; ++rt)
            a[rt] = *(const bf16x8*)&AL[(rt * 16 + lr) * 136 + ks * 32 + lg * 8];
#pragma unroll
        for (int ct = 0; ct < 2; ++ct) {
            int col = j0 + w * 32 + ct * 16 + lr;
            b[ct] = *(const bf16x8*)&Wgp[(size_t)((ks * 4 + lg) * 512 + col) * 8];
        }
#pragma unroll
        for (int rt = 0; rt < 4; ++rt)
#pragma unroll
            for (int ct = 0; ct < 2; ++ct)
                acc[rt][ct] = __builtin_amdgcn_mfma_f32_16x16x32_bf16(a[rt], b[ct], acc[rt][ct], 0, 0, 0);
    }
#pragma unroll
    for (int rt = 0; rt < 4; ++rt)
#pragma unroll
        for (int ct = 0; ct < 2; ++ct) {
            int col = j0 + w * 32 + ct * 16 + lr;
#pragma unroll
            for (int i = 0; i < 4; ++i) {
                int row = rb + rt * 16 + lg * 4 + i;
                if (row < N_NODES) xhb[(size_t)row * 512 + col] = f2b(acc[rt][ct][i]);
            }
        }
}

// ---------------- es/ed from bf16 xh ----------------
__global__ void esed_kernel(const u16* __restrict__ xhb, const float* __restrict__ ags,
                            const float* __restrict__ agd, float* __restrict__ es,
                            float* __restrict__ ed) {
    int wv = threadIdx.x >> 6, lane = threadIdx.x & 63;
    int n = blockIdx.x * 4 + wv;
    if (n >= N_NODES) return;
    u16x8 v = *(const u16x8*)&xhb[(size_t)n * 512 + lane * 8];
    float ps = 0.f, pd = 0.f;
#pragma unroll
    for (int j = 0; j < 8; ++j) {
        float f = b2f(v[j]);
        ps = fmaf(f, ags[lane * 8 + j], ps);
        pd = fmaf(f, agd[lane * 8 + j], pd);
    }
#pragma unroll
    for (int off = 1; off < 16; off <<= 1) {
        ps += __shfl_xor(ps, off);
        pd += __shfl_xor(pd, off);
    }
    if ((lane & 15) == 0) {
        es[n * 4 + (lane >> 4)] = ps;
        ed[n * 4 + (lane >> 4)] = pd;
    }
}

// ---------------- GAT aggregation (bf16 xh): one wave per dst node ----------------
__global__ __launch_bounds__(64) void gat_agg_kernel(const u16* __restrict__ xhb,
                               const float* __restrict__ es, const float* __restrict__ ed,
                               const int* __restrict__ rowstart, const int* __restrict__ csr_src,
                               const float* __restrict__ bg, float* __restrict__ h,
                               u16* __restrict__ hb) {
    __shared__ float aL[64][4];
    __shared__ int sL[64];
    int n = blockIdx.x;
    int lane = threadIdx.x;
    int r0 = rowstart[n], r1 = rowstart[n + 1];
    int deg = r1 - r0;
    const float4 ed4 = ((const float4*)ed)[n];
    const float edh[4] = {ed4.x, ed4.y, ed4.z, ed4.w};
    float mx[4] = {-3.4e38f, -3.4e38f, -3.4e38f, -3.4e38f};
    for (int j = lane; j < deg; j += 64) {
        int s = csr_src[r0 + j];
        const float4 e4 = ((const float4*)es)[s];
        const float ev[4] = {e4.x, e4.y, e4.z, e4.w};
#pragma unroll
        for (int hh = 0; hh < 4; ++hh) {
            float e = ev[hh] + edh[hh];
            e = e > 0.f ? e : 0.2f * e;
            mx[hh] = fmaxf(mx[hh], e);
        }
    }
#pragma unroll
    for (int hh = 0; hh < 4; ++hh)
        for (int off = 32; off; off >>= 1) mx[hh] = fmaxf(mx[hh], __shfl_xor(mx[hh], off));
    float den[4] = {0.f, 0.f, 0.f, 0.f};
    for (int j = lane; j < deg; j += 64) {
        int s = csr_src[r0 + j];
        const float4 e4 = ((const float4*)es)[s];
        const float ev[4] = {e4.x, e4.y, e4.z, e4.w};
#pragma unroll
        for (int hh = 0; hh < 4; ++hh) {
            float e = ev[hh] + edh[hh];
            e = e > 0.f ? e : 0.2f * e;
            den[hh] += __expf(e - mx[hh]);
        }
    }
#pragma unroll
    for (int hh = 0; hh < 4; ++hh) {
        for (int off = 32; off; off >>= 1) den[hh] += __shfl_xor(den[hh], off);
        den[hh] = 1.f / den[hh];
    }
    float acc[8] = {0.f, 0.f, 0.f, 0.f, 0.f, 0.f, 0.f, 0.f};
    int head = lane >> 4, c0 = (lane & 15) * 8;
    for (int base = 0; base < deg; base += 64) {
        int j = base + lane;
        if (j < deg) {
            int s = csr_src[r0 + j];
            sL[lane] = s;
            const float4 e4 = ((const float4*)es)[s];
            const float ev[4] = {e4.x, e4.y, e4.z, e4.w};
            float al[4];
#pragma unroll
            for (int hh = 0; hh < 4; ++hh) {
                float e = ev[hh] + edh[hh];
                e = e > 0.f ? e : 0.2f * e;
                al[hh] = __expf(e - mx[hh]) * den[hh];
            }
            *(float4*)&aL[lane][0] = make_float4(al[0], al[1], al[2], al[3]);
        }
        __syncthreads();
        int cnt = min(64, deg - base);
        for (int j2 = 0; j2 < cnt; ++j2) {
            int s = sL[j2];
            float al = aL[j2][head];
            u16x8 v = *(const u16x8*)&xhb[(size_t)s * 512 + head * 128 + c0];
#pragma unroll
            for (int m = 0; m < 8; ++m) acc[m] = fmaf(al, b2f(v[m]), acc[m]);
        }
        __syncthreads();
    }
#pragma unroll
    for (int m = 0; m < 8; ++m) {
        float v = acc[m];
        v += __shfl_xor(v, 16);
        v += __shfl_xor(v, 32);
        acc[m] = v;
    }
    if (lane < 16) {
        float o8[8];
        u16x8 b8;
#pragma unroll
        for (int m = 0; m < 8; ++m) {
            int c = lane * 8 + m;
            float o = acc[m] * 0.25f + bg[c];
            o = fmaxf(o, 0.f);
            float hn = h[(size_t)n * 128 + c] + o;
            o8[m] = hn;
            b8[m] = f2b(hn);
        }
        *(float4*)&h[(size_t)n * 128 + lane * 8] = make_float4(o8[0], o8[1], o8[2], o8[3]);
        *(float4*)&h[(size_t)n * 128 + lane * 8 + 4] = make_float4(o8[4], o8[5], o8[6], o8[7]);
        *(u16x8*)&hb[(size_t)n * 128 + lane * 8] = b8;
    }
}

// ---------------- pooling via binary search (batch sorted) ----------------
__global__ void pool_bs_kernel(const float* __restrict__ h, const int* __restrict__ batch,
                               float* __restrict__ pr0) {
    int g = blockIdx.x, t = threadIdx.x;
    int lo = 0, hi = N_NODES;
    while (lo < hi) { int m = (lo + hi) >> 1; if (batch[m] < g) lo = m + 1; else hi = m; }
    int s = lo;
    lo = 0; hi = N_NODES;
    while (lo < hi) { int m = (lo + hi) >> 1; if (batch[m] < g + 1) lo = m + 1; else hi = m; }
    int e = lo;
    float acc = 0.f;
    for (int n = s; n < e; ++n) acc += h[(size_t)n * HID + t];
    float c = fmaxf((float)(e - s), 1.f);
    pr0[g * HID + t] = acc / c;
}

// ---------------- z = mu + eps * exp(0.5*logvar) ----------------
__global__ void z_kernel(const float* __restrict__ mu, const float* __restrict__ lv,
                         const float* __restrict__ eps, float* __restrict__ z) {
    int i = blockIdx.x * blockDim.x + threadIdx.x;
    if (i < N_GRAPHS * LAT) z[i] = fmaf(eps[i], __expf(0.5f * lv[i]), mu[i]);
}

__global__ void sigmoid_kernel(const float* __restrict__ in, float* __restrict__ out, int n) {
    int i = blockIdx.x * blockDim.x + threadIdx.x;
    if (i < n) out[i] = 1.f / (1.f + __expf(-in[i]));
}

// ---------------- triu pair indices ----------------
__global__ void pairs_kernel(int* __restrict__ pi, int* __restrict__ pj) {
    int p = blockIdx.x * blockDim.x + threadIdx.x;
    if (p >= NPAIR) return;
    int i = 0, off = 0;
    while (off + (MAXN - 1 - i) <= p) { off += MAXN - 1 - i; ++i; }
    pi[p] = i;
    pj[p] = i + 1 + (p - off);
}

// ---------------- fused edge + reaction MLPs via MFMA, 64 rows per block ----------------
// grid (20, 64): blockIdx.y = graph b, blockIdx.x = pair chunk (64 pairs)
__global__ __launch_bounds__(256) void edge_react_mfma(
    const u16* __restrict__ zb, const u16* __restrict__ nb,
    const int* __restrict__ pi, const int* __restrict__ pj,
    const u16* __restrict__ We1p, const float* __restrict__ be1,
    const u16* __restrict__ We2p, const float* __restrict__ be2,
    const float* __restrict__ We3, const float* __restrict__ be3,
    const u16* __restrict__ Wr1p, const float* __restrict__ br1,
    const float* __restrict__ Wr2, const float* __restrict__ br2,
    float* __restrict__ edgep, float* __restrict__ react) {
    __shared__ u16 inA[64 * 200];   // rows of 192 bf16, stride 200; later reused for h2 (64x68)
    __shared__ u16 h1A[64 * 136];   // 128 cols, stride 136
    __shared__ u16 rhA[64 * 68];    // 64 cols, stride 68
    int t = threadIdx.x, w = t >> 6, l = t & 63, lr = l & 15, lg = l >> 4;
    int b = blockIdx.y, p0 = blockIdx.x * 64;
    // gather input rows [z | n_i | n_j] in bf16
    for (int u = t; u < 1536; u += 256) {
        int r = u / 24, c8 = (u % 24) * 8;
        int p = min(p0 + r, NPAIR - 1);
        const u16* src;
        if (c8 < 64) src = zb + b * 64 + c8;
        else if (c8 < 128) src = nb + b * NODESF + pi[p] * 64 + (c8 - 64);
        else src = nb + b * NODESF + pj[p] * 64 + (c8 - 128);
        *(u16x8*)&inA[r * 200 + c8] = *(const u16x8*)src;
    }
    __syncthreads();
    // L1: 192 -> 128, wave w owns cols w*32 .. +31
    f32x4 a1[4][2];
#pragma unroll
    for (int rt = 0; rt < 4; ++rt)
#pragma unroll
        for (int ct = 0; ct < 2; ++ct) a1[rt][ct] = (f32x4){0.f, 0.f, 0.f, 0.f};
#pragma unroll
    for (int ks = 0; ks < 6; ++ks) {
        bf16x8 af[4], bf_[2];
#pragma unroll
        for (int rt = 0; rt < 4; ++rt)
            af[rt] = *(const bf16x8*)&inA[(rt * 16 + lr) * 200 + ks * 32 + lg * 8];
#pragma unroll
        for (int ct = 0; ct < 2; ++ct) {
            int col = w * 32 + ct * 16 + lr;
            bf_[ct] = *(const bf16x8*)&We1p[(size_t)((ks * 4 + lg) * 128 + col) * 8];
        }
#pragma unroll
        for (int rt = 0; rt < 4; ++rt)
#pragma unroll
            for (int ct = 0; ct < 2; ++ct)
                a1[rt][ct] = __builtin_amdgcn_mfma_f32_16x16x32_bf16(af[rt], bf_[ct], a1[rt][ct], 0, 0, 0);
    }
    // R1: cols 64..191 of inA (128 wide) -> 64, wave w owns cols w*16 .. +15
    f32x4 r1[4];
#pragma unroll
    for (int rt = 0; rt < 4; ++rt) r1[rt] = (f32x4){0.f, 0.f, 0.f, 0.f};
#pragma unroll
    for (int ks = 0; ks < 4; ++ks) {
        bf16x8 af[4];
#pragma unroll
        for (int rt = 0; rt < 4; ++rt)
            af[rt] = *(const bf16x8*)&inA[(rt * 16 + lr) * 200 + 64 + ks * 32 + lg * 8];
        int col = w * 16 + lr;
        bf16x8 bf_ = *(const bf16x8*)&Wr1p[(size_t)((ks * 4 + lg) * 64 + col) * 8];
#pragma unroll
        for (int rt = 0; rt < 4; ++rt)
            r1[rt] = __builtin_amdgcn_mfma_f32_16x16x32_bf16(af[rt], bf_, r1[rt], 0, 0, 0);
    }
    // write h1 (relu + bias), rh (relu + bias)
#pragma unroll
    for (int rt = 0; rt < 4; ++rt)
#pragma unroll
        for (int ct = 0; ct < 2; ++ct) {
            int col = w * 32 + ct * 16 + lr;
            float bia = be1[col];
#pragma unroll
            for (int i = 0; i < 4; ++i) {
                int row = rt * 16 + lg * 4 + i;
                h1A[row * 136 + col] = f2b(fmaxf(a1[rt][ct][i] + bia, 0.f));
            }
        }
#pragma unroll
    for (int rt = 0; rt < 4; ++rt) {
        int col = w * 16 + lr;
        float bia = br1[col];
#pragma unroll
        for (int i = 0; i < 4; ++i) {
            int row = rt * 16 + lg * 4 + i;
            rhA[row * 68 + col] = f2b(fmaxf(r1[rt][i] + bia, 0.f));
        }
    }
    __syncthreads();
    // L2: 128 -> 64, wave w owns cols w*16 .. +15
    f32x4 a2[4];
#pragma unroll
    for (int rt = 0; rt < 4; ++rt) a2[rt] = (f32x4){0.f, 0.f, 0.f, 0.f};
#pragma unroll
    for (int ks = 0; ks < 4; ++ks) {
        bf16x8 af[4];
#pragma unroll
        for (int rt = 0; rt < 4; ++rt)
            af[rt] = *(const bf16x8*)&h1A[(rt * 16 + lr) * 136 + ks * 32 + lg * 8];
        int col = w * 16 + lr;
        bf16x8 bf_ = *(const bf16x8*)&We2p[(size_t)((ks * 4 + lg) * 64 + col) * 8];
#pragma unroll
        for (int rt = 0; rt < 4; ++rt)
            a2[rt] = __builtin_amdgcn_mfma_f32_16x16x32_bf16(af[rt], bf_, a2[rt], 0, 0, 0);
    }
    // h2 reuses inA space (all inA reads completed before previous barrier)
    u16* h2A = inA;
#pragma unroll
    for (int rt = 0; rt < 4; ++rt) {
        int col = w * 16 + lr;
        float bia = be2[col];
#pragma unroll
        for (int i = 0; i < 4; ++i) {
            int row = rt * 16 + lg * 4 + i;
            h2A[row * 68 + col] = f2b(fmaxf(a2[rt][i] + bia, 0.f));
        }
    }
    __syncthreads();
    // L3: 64 -> 1 sigmoid ; R2: 64 -> 6 softmax  (4 threads per row)
    int r = t >> 2, sub = t & 3;
    int p = p0 + r;
    float acc3 = 0.f;
#pragma unroll
    for (int kk = 0; kk < 16; ++kk) {
        int c = sub * 16 + kk;
        acc3 = fmaf(b2f(h2A[r * 68 + c]), We3[c], acc3);
    }
    acc3 += __shfl_xor(acc3, 1);
    acc3 += __shfl_xor(acc3, 2);
    if (sub == 0 && p < NPAIR)
        edgep[b * NPAIR + p] = 1.f / (1.f + __expf(-(acc3 + be3[0])));
    float lg6[6] = {0.f, 0.f, 0.f, 0.f, 0.f, 0.f};
#pragma unroll
    for (int kk = 0; kk < 16; ++kk) {
        int c = sub * 16 + kk;
        float v = b2f(rhA[r * 68 + c]);
#pragma unroll
        for (int m = 0; m < 6; ++m) lg6[m] = fmaf(v, Wr2[c * 6 + m], lg6[m]);
    }
#pragma unroll
    for (int m = 0; m < 6; ++m) {
        lg6[m] += __shfl_xor(lg6[m], 1);
        lg6[m] += __shfl_xor(lg6[m], 2);
    }
    if (sub == 0 && p < NPAIR) {
        float mx = -3.4e38f;
#pragma unroll
        for (int m = 0; m < 6; ++m) { lg6[m] += br2[m]; mx = fmaxf(mx, lg6[m]); }
        float s = 0.f;
        float ex[6];
#pragma unroll
        for (int m = 0; m < 6; ++m) { ex[m] = __expf(lg6[m] - mx); s += ex[m]; }
        float rs = 1.f / s;
#pragma unroll
        for (int m = 0; m < 6; ++m) react[(size_t)(b * NPAIR + p) * 6 + m] = ex[m] * rs;
    }
}

// ---------------- launch ----------------
extern "C" void kernel_launch(void* const* d_in, const int* in_sizes, int n_in,
                              void* d_out, int out_size, void* d_ws, size_t ws_size,
                              hipStream_t stream) {
    const float* x     = (const float*)d_in[0];
    const int*   ei    = (const int*)d_in[1];
    const int*   batch = (const int*)d_in[2];
    const float* eps   = (const float*)d_in[3];
    const float* We    = (const float*)d_in[4];
    const float* be    = (const float*)d_in[5];
    const float* Wg    = (const float*)d_in[6];
    const float* ags   = (const float*)d_in[7];
    const float* agd   = (const float*)d_in[8];
    const float* bg    = (const float*)d_in[9];
    const float* Wa1   = (const float*)d_in[10];
    const float* ba1   = (const float*)d_in[11];
    const float* Wa2   = (const float*)d_in[12];
    const float* ba2   = (const float*)d_in[13];
    const float* Wmu   = (const float*)d_in[14];
    const float* bmu   = (const float*)d_in[15];
    const float* Wlv   = (const float*)d_in[16];
    const float* blv   = (const float*)d_in[17];
    const float* Wn1   = (const float*)d_in[18];
    const float* bn1   = (const float*)d_in[19];
    const float* Wn2   = (const float*)d_in[20];
    const float* bn2   = (const float*)d_in[21];
    const float* Wn3   = (const float*)d_in[22];
    const float* bn3   = (const float*)d_in[23];
    const float* We1   = (const float*)d_in[24];
    const float* be1   = (const float*)d_in[25];
    const float* We2   = (const float*)d_in[26];
    const float* be2   = (const float*)d_in[27];
    const float* We3   = (const float*)d_in[28];
    const float* be3   = (const float*)d_in[29];
    const float* Wr1   = (const float*)d_in[30];
    const float* br1   = (const float*)d_in[31];
    const float* Wr2   = (const float*)d_in[32];
    const float* br2   = (const float*)d_in[33];

    float* out = (float*)d_out;
    float* mu_o    = out;
    float* lv_o    = out + 4096;
    float* z_o     = out + 8192;
    float* pr_o    = out + 12288;
    float* nodep_o = out + 20480;
    float* edgep_o = out + 225280;
    float* react_o = out + 303680;

    float* F = (float*)d_ws;
    size_t o = 0;
    float* h      = F + o; o += (size_t)N_NODES * HID;       // 1,280,000
    float* es     = F + o; o += (size_t)N_NODES * 4;
    float* ed     = F + o; o += (size_t)N_NODES * 4;
    float* t1     = F + o; o += 64 * 256;
    float* g1b    = F + o; o += 64 * 256;
    float* g2b    = F + o; o += 64 * 512;
    float* nodesb = F + o; o += 64 * NODESF;
    float* pr0    = F + o; o += 64 * HID;
    u16* hb     = (u16*)(F + o); o += (size_t)N_NODES * HID / 2;      // bf16 shadow of h
    u16* xhb    = (u16*)(F + o); o += (size_t)N_NODES * HC / 2;       // bf16 xh
    u16* zbf    = (u16*)(F + o); o += 4096 / 2;
    u16* nbf    = (u16*)(F + o); o += 64 * NODESF / 2;
    u16* Wgp    = (u16*)(F + o); o += 3 * 128 * HC / 2;
    u16* We1p   = (u16*)(F + o); o += 192 * 128 / 2;
    u16* We2p   = (u16*)(F + o); o += 128 * 64 / 2;
    u16* Wr1p   = (u16*)(F + o); o += 128 * 64 / 2;
    int* I = (int*)(F + o);
    int* rowstart = I;
    int* csr_src  = I + (N_NODES + 1);
    int* piA      = I + (N_NODES + 1) + E_TOT;
    int* pjA      = piA + NPAIR;
    int* deg      = pjA + NPAIR;        // zeroed
    int* cursor   = deg + N_NODES;      // zeroed

    hipMemsetAsync(deg, 0, (size_t)N_NODES * 2 * sizeof(int), stream);

    pairs_kernel<<<5, 256, 0, stream>>>(piA, pjA);
    deg_kernel<<<(E_TOT + 255) / 256, 256, 0, stream>>>(ei, deg);
    scan_kernel<<<1, 1024, 0, stream>>>(deg, rowstart);
    fill_kernel<<<(E_TOT + 255) / 256, 256, 0, stream>>>(ei, rowstart, cursor, csr_src);

    // pack weights to bf16 B-fragment layout
    for (int l = 0; l < 3; ++l)
        pack_b_kernel<<<(16 * 512 + 255) / 256, 256, 0, stream>>>(
            Wg + (size_t)l * 128 * HC, Wgp + (size_t)l * 128 * HC, 16, 512);
    pack_b_kernel<<<(24 * 128 + 255) / 256, 256, 0, stream>>>(We1, We1p, 24, 128);
    pack_b_kernel<<<(16 * 64 + 255) / 256, 256, 0, stream>>>(We2, We2p, 16, 64);
    pack_b_kernel<<<(16 * 64 + 255) / 256, 256, 0, stream>>>(Wr1, Wr1p, 16, 64);

    // h = relu(x @ We + be), then bf16 shadow
    bdense_kernel<1, 8, 128><<<dim3(N_NODES / 16, 1), 256, 16 * 64 * 4, stream>>>(
        x, We, be, h, 64, 6, 128);
    convf2b_kernel<<<(N_NODES * HID + 255) / 256, 256, 0, stream>>>(h, hb, N_NODES * HID);

    // 3 GAT layers
    for (int l = 0; l < 3; ++l) {
        gemm_h_kernel<<<dim3((N_NODES + 63) / 64, 4), 256, 0, stream>>>(
            hb, Wgp + (size_t)l * 128 * HC, xhb);
        esed_kernel<<<N_NODES / 4, 256, 0, stream>>>(xhb, ags + l * HC, agd + l * HC, es, ed);
        gat_agg_kernel<<<N_NODES, 64, 0, stream>>>(xhb, es, ed, rowstart, csr_src,
                                                   bg + l * HID, h, hb);
    }

    // pooling -> pr chain
    pool_bs_kernel<<<N_GRAPHS, HID, 0, stream>>>(h, batch, pr0);
    bdense_kernel<1, 8, 128><<<dim3(4, 2), 256, 16 * 128 * 4, stream>>>(pr0, Wa1, ba1, t1, 128, 7, 256);
    bdense_kernel<0, 8, 128><<<dim3(4, 1), 256, 16 * 256 * 4, stream>>>(t1, Wa2, ba2, pr_o, 256, 8, 128);
    bdense_kernel<0, 4, 64><<<dim3(4, 1), 256, 16 * 128 * 4, stream>>>(pr_o, Wmu, bmu, mu_o, 128, 7, 64);
    bdense_kernel<0, 4, 64><<<dim3(4, 1), 256, 16 * 128 * 4, stream>>>(pr_o, Wlv, blv, lv_o, 128, 7, 64);
    z_kernel<<<16, 256, 0, stream>>>(mu_o, lv_o, eps, z_o);
    convf2b_kernel<<<(4096 + 255) / 256, 256, 0, stream>>>(z_o, zbf, 4096);

    // decoder
    bdense_kernel<1, 8, 128><<<dim3(4, 2), 256, 16 * 64 * 4, stream>>>(z_o, Wn1, bn1, g1b, 64, 6, 256);
    bdense_kernel<1, 8, 128><<<dim3(4, 4), 256, 16 * 256 * 4, stream>>>(g1b, Wn2, bn2, g2b, 256, 8, 512);
    bdense_kernel<0, 8, 128><<<dim3(4, 25), 256, 16 * 512 * 4, stream>>>(g2b, Wn3, bn3, nodesb, 512, 9, 3200);
    sigmoid_kernel<<<(64 * NODESF) / 256, 256, 0, stream>>>(nodesb, nodep_o, 64 * NODESF);
    convf2b_kernel<<<(64 * NODESF + 255) / 256, 256, 0, stream>>>(nodesb, nbf, 64 * NODESF);

    // fused edge + reaction MLPs (MFMA)
    edge_react_mfma<<<dim3(20, 64), 256, 0, stream>>>(
        zbf, nbf, piA, pjA, We1p, be1, We2p, be2, We3, be3,
        Wr1p, br1, Wr2, br2, edgep_o, react_o);
}

// Round 4
// 293.158 us; speedup vs baseline: 2.4725x; 1.4389x over previous
//
#include <hip/hip_runtime.h>
#include <cstddef>

#define N_NODES 10000
#define N_EDGES 160000
#define E_TOT   170000
#define N_GRAPHS 64
#define NF 64
#define HID 128
#define HC 512
#define LAT 64
#define MAXN 50
#define NPAIR 1225
#define NODESF 3200

typedef __attribute__((ext_vector_type(8))) short bf16x8;
typedef __attribute__((ext_vector_type(8))) unsigned short u16x8;
typedef __attribute__((ext_vector_type(4))) float f32x4;
typedef unsigned short u16;
typedef unsigned int u32;

__device__ __forceinline__ u16 f2b(float f) {
    u32 u = __float_as_uint(f);
    u32 r = (u + 0x7fffu + ((u >> 16) & 1u)) >> 16;
    return (u16)r;
}
__device__ __forceinline__ float b2f(u16 v) {
    return __uint_as_float(((u32)v) << 16);
}

// ================= pack_all: every weight -> bf16 B-fragment layout, + x -> bf16 =================
// B layout: Wp[(g*dN + n + coff)*8 + j] = bf16(W[(g*8+j)*N + n])
struct PackArgs {
    const float* src[15];
    u16* dst[15];
};
#define PACK_TOTAL 344192
__global__ void pack_all_kernel(PackArgs pa) {
    int idx = blockIdx.x * 256 + threadIdx.x;
    if (idx >= PACK_TOTAL) return;
    const int base[16] = {0, 8192, 16384, 24576, 27648, 28672, 29696, 33792, 37888,
                          38912, 39936, 41984, 58368, 263168, 264192, 344192};
    const int Ns[15]   = {512, 512, 512, 128, 64, 64, 256, 128, 64, 64, 256, 512, 3200, 128, 0};
    const int dNs[15]  = {512, 512, 512, 128, 64, 64, 256, 128, 128, 128, 256, 512, 3200, 128, 0};
    const int coff[15] = {0, 0, 0, 0, 0, 0, 0, 0, 0, 64, 0, 0, 0, 0, 0};
    int s = 0;
    while (idx >= base[s + 1]) ++s;
    int i = idx - base[s];
    const float* sp = pa.src[s];
    u16* dp = pa.dst[s];
    if (s == 14) {  // x conversion: 8 consecutive elements
        u16x8 o;
#pragma unroll
        for (int j = 0; j < 8; ++j) o[j] = f2b(sp[(size_t)i * 8 + j]);
        *(u16x8*)&dp[(size_t)i * 8] = o;
        return;
    }
    int N = Ns[s];
    int g = i / N, n = i - g * N;
    u16x8 o;
#pragma unroll
    for (int j = 0; j < 8; ++j) o[j] = f2b(sp[(size_t)(g * 8 + j) * N + n]);
    *(u16x8*)&dp[((size_t)g * dNs[s] + n + coff[s]) * 8] = o;
}

// ================= CSR build =================
__global__ void deg_kernel(const int* __restrict__ ei, int* __restrict__ deg) {
    int e = blockIdx.x * blockDim.x + threadIdx.x;
    if (e >= E_TOT) return;
    int d = (e < N_EDGES) ? ei[N_EDGES + e] : (e - N_EDGES);
    atomicAdd(&deg[d], 1);
}

__global__ void scan_kernel(const int* __restrict__ deg, int* __restrict__ rowstart) {
    __shared__ int wsum[16];
    __shared__ int carry_s;
    int lane = threadIdx.x & 63, wv = threadIdx.x >> 6;
    if (threadIdx.x == 0) carry_s = 0;
    __syncthreads();
    for (int base = 0; base < N_NODES; base += 1024) {
        int i = base + (int)threadIdx.x;
        int v = (i < N_NODES) ? deg[i] : 0;
        int s = v;
#pragma unroll
        for (int d = 1; d < 64; d <<= 1) {
            int u = __shfl_up(s, d);
            if (lane >= d) s += u;
        }
        if (lane == 63) wsum[wv] = s;
        __syncthreads();
        if (wv == 0 && lane < 16) {
            int ws = wsum[lane];
            int t2 = ws;
#pragma unroll
            for (int d = 1; d < 16; d <<= 1) {
                int u = __shfl_up(t2, d);
                if (lane >= d) t2 += u;
            }
            wsum[lane] = t2 - ws;  // exclusive wave offset
        }
        __syncthreads();
        int incl = s + wsum[wv] + carry_s;
        if (i < N_NODES) rowstart[i] = incl - v;
        __syncthreads();
        if (threadIdx.x == 1023) carry_s = incl;
        __syncthreads();
    }
    if (threadIdx.x == 0) rowstart[N_NODES] = carry_s;
}

__global__ void fill_kernel(const int* __restrict__ ei, const int* __restrict__ rowstart,
                            int* __restrict__ cursor, int* __restrict__ csr_src) {
    int e = blockIdx.x * blockDim.x + threadIdx.x;
    if (e >= E_TOT) return;
    int s, d;
    if (e < N_EDGES) { s = ei[e]; d = ei[N_EDGES + e]; }
    else { s = e - N_EDGES; d = s; }
    int pos = atomicAdd(&cursor[d], 1);
    csr_src[rowstart[d] + pos] = s;
}

// ================= gemm_mh: M-large MFMA GEMM, 64 rows x 128 cols per block =================
// A [M x K] bf16 row-major, Wp packed [(K/8)][NT][8], out col block j0 = blockIdx.y*128
template<int K, int NT, bool BIAS, bool RELU, bool F32OUT>
__global__ __launch_bounds__(256) void gemm_mh_kernel(const u16* __restrict__ A,
                                                      const u16* __restrict__ Wp,
                                                      const float* __restrict__ bias,
                                                      u16* __restrict__ bo,
                                                      float* __restrict__ fo) {
    __shared__ u16 AL[64 * (K + 8)];
    int t = threadIdx.x, w = t >> 6, l = t & 63, lr = l & 15, lg = l >> 4;
    int rb = blockIdx.x * 64, j0 = blockIdx.y * 128;
    for (int u = t; u < 64 * (K / 8); u += 256) {
        int r = u / (K / 8), c8 = (u % (K / 8)) * 8;
        int row = min(rb + r, N_NODES - 1);
        *(u16x8*)&AL[r * (K + 8) + c8] = *(const u16x8*)&A[(size_t)row * K + c8];
    }
    __syncthreads();
    f32x4 acc[4][2];
#pragma unroll
    for (int rt = 0; rt < 4; ++rt)
#pragma unroll
        for (int ct = 0; ct < 2; ++ct) acc[rt][ct] = (f32x4){0.f, 0.f, 0.f, 0.f};
#pragma unroll
    for (int ks = 0; ks < K / 32; ++ks) {
        bf16x8 a[4], b[2];
#pragma unroll
        for (int rt = 0; rt < 4; ++rt)
            a[rt] = *(const bf16x8*)&AL[(rt * 16 + lr) * (K + 8) + ks * 32 + lg * 8];
#pragma unroll
        for (int ct = 0; ct < 2; ++ct) {
            int col = j0 + w * 32 + ct * 16 + lr;
            b[ct] = *(const bf16x8*)&Wp[(size_t)((ks * 4 + lg) * NT + col) * 8];
        }
#pragma unroll
        for (int rt = 0; rt < 4; ++rt)
#pragma unroll
            for (int ct = 0; ct < 2; ++ct)
                acc[rt][ct] = __builtin_amdgcn_mfma_f32_16x16x32_bf16(a[rt], b[ct], acc[rt][ct], 0, 0, 0);
    }
#pragma unroll
    for (int rt = 0; rt < 4; ++rt)
#pragma unroll
        for (int ct = 0; ct < 2; ++ct) {
            int col = j0 + w * 32 + ct * 16 + lr;
            float bj = BIAS ? bias[col] : 0.f;
#pragma unroll
            for (int i = 0; i < 4; ++i) {
                int row = rb + rt * 16 + lg * 4 + i;
                if (row < N_NODES) {
                    float v = acc[rt][ct][i] + bj;
                    if (RELU) v = fmaxf(v, 0.f);
                    bo[(size_t)row * NT + col] = f2b(v);
                    if (F32OUT) fo[(size_t)row * NT + col] = v;
                }
            }
        }
}

// ================= gemm64: M=64 skinny MFMA GEMM with intra-block split-K =================
// 4 waves; G waves share a 16-col group splitting K; NB = (4/G)*16 cols per block.
// ACT: 0 none, 1 relu, 2 sigmoid->fo & raw->bo. SPLIT: cols<64 -> fo, cols>=64 -> fo2 (ldc 64).
template<int K, int G, int ACT, bool SPLIT>
__global__ __launch_bounds__(256) void gemm64_kernel(const u16* __restrict__ A,
                                                     const u16* __restrict__ Wp,
                                                     const float* __restrict__ bias,
                                                     const float* __restrict__ bias2,
                                                     float* __restrict__ fo,
                                                     float* __restrict__ fo2,
                                                     u16* __restrict__ bo, int N) {
    constexpr int CG = 4 / G, NB = CG * 16, Kc = K / G, KS = Kc / 32;
    constexpr int ABYTES = 64 * (K + 8) * 2;
    constexpr int LDSB = (ABYTES > 16384) ? ABYTES : 16384;
    __shared__ float LDSf[LDSB / 4];
    u16* AL = (u16*)LDSf;
    float* RB = LDSf;
    int t = threadIdx.x, w = t >> 6, l = t & 63, lr = l & 15, lg = l >> 4;
    for (int u = t; u < 64 * (K / 8); u += 256) {
        int r = u / (K / 8), c8 = (u % (K / 8)) * 8;
        *(u16x8*)&AL[r * (K + 8) + c8] = *(const u16x8*)&A[(size_t)r * K + c8];
    }
    __syncthreads();
    int kg = w % G, cg = w / G;
    int col = blockIdx.x * NB + cg * 16 + lr;
    f32x4 acc[4];
#pragma unroll
    for (int rt = 0; rt < 4; ++rt) acc[rt] = (f32x4){0.f, 0.f, 0.f, 0.f};
#pragma unroll
    for (int ks = 0; ks < KS; ++ks) {
        int k0 = kg * Kc + ks * 32;
        bf16x8 b = *(const bf16x8*)&Wp[(size_t)(((k0 >> 3) + lg) * N + col) * 8];
#pragma unroll
        for (int rt = 0; rt < 4; ++rt) {
            bf16x8 a = *(const bf16x8*)&AL[(rt * 16 + lr) * (K + 8) + k0 + lg * 8];
            acc[rt] = __builtin_amdgcn_mfma_f32_16x16x32_bf16(a, b, acc[rt], 0, 0, 0);
        }
    }
    __syncthreads();  // all AL reads done; alias LDS to reduce buffer
#pragma unroll
    for (int rt = 0; rt < 4; ++rt)
#pragma unroll
        for (int i = 0; i < 4; ++i)
            RB[w * 1024 + (rt * 16 + lg * 4 + i) * 16 + lr] = acc[rt][i];
    __syncthreads();
    for (int e = t; e < 64 * NB; e += 256) {
        int row = e / NB, cb = e - row * NB;
        int cg2 = cb >> 4, cl = cb & 15;
        float s = 0.f;
#pragma unroll
        for (int kg2 = 0; kg2 < G; ++kg2)
            s += RB[(cg2 * G + kg2) * 1024 + row * 16 + cl];
        int c = blockIdx.x * NB + cb;
        float bj;
        if (SPLIT) bj = (c < 64) ? bias[c] : bias2[c - 64];
        else bj = bias[c];
        float v = s + bj;
        if (ACT == 1) v = fmaxf(v, 0.f);
        if (bo) bo[(size_t)row * N + c] = f2b(v);
        if (SPLIT) {
            if (c < 64) fo[row * 64 + c] = v;
            else fo2[row * 64 + (c - 64)] = v;
        } else if (fo) {
            float ov = (ACT == 2) ? 1.f / (1.f + __expf(-v)) : v;
            fo[(size_t)row * N + c] = ov;
        }
    }
}

// ================= es/ed from bf16 xh =================
__global__ void esed_kernel(const u16* __restrict__ xhb, const float* __restrict__ ags,
                            const float* __restrict__ agd, float* __restrict__ es,
                            float* __restrict__ ed) {
    int wv = threadIdx.x >> 6, lane = threadIdx.x & 63;
    int n = blockIdx.x * 4 + wv;
    if (n >= N_NODES) return;
    u16x8 v = *(const u16x8*)&xhb[(size_t)n * 512 + lane * 8];
    float ps = 0.f, pd = 0.f;
#pragma unroll
    for (int j = 0; j < 8; ++j) {
        float f = b2f(v[j]);
        ps = fmaf(f, ags[lane * 8 + j], ps);
        pd = fmaf(f, agd[lane * 8 + j], pd);
    }
#pragma unroll
    for (int off = 1; off < 16; off <<= 1) {
        ps += __shfl_xor(ps, off);
        pd += __shfl_xor(pd, off);
    }
    if ((lane & 15) == 0) {
        es[n * 4 + (lane >> 4)] = ps;
        ed[n * 4 + (lane >> 4)] = pd;
    }
}

// ================= GAT aggregation: one wave per dst node =================
__global__ __launch_bounds__(64) void gat_agg_kernel(const u16* __restrict__ xhb,
                               const float* __restrict__ es, const float* __restrict__ ed,
                               const int* __restrict__ rowstart, const int* __restrict__ csr_src,
                               const float* __restrict__ bg, float* __restrict__ h,
                               u16* __restrict__ hb) {
    __shared__ float aL[64][4];
    __shared__ int sL[64];
    int n = blockIdx.x;
    int lane = threadIdx.x;
    int r0 = rowstart[n], r1 = rowstart[n + 1];
    int deg = r1 - r0;
    const float4 ed4 = ((const float4*)ed)[n];
    const float edh[4] = {ed4.x, ed4.y, ed4.z, ed4.w};
    float mx[4] = {-3.4e38f, -3.4e38f, -3.4e38f, -3.4e38f};
    for (int j = lane; j < deg; j += 64) {
        int s = csr_src[r0 + j];
        const float4 e4 = ((const float4*)es)[s];
        const float ev[4] = {e4.x, e4.y, e4.z, e4.w};
#pragma unroll
        for (int hh = 0; hh < 4; ++hh) {
            float e = ev[hh] + edh[hh];
            e = e > 0.f ? e : 0.2f * e;
            mx[hh] = fmaxf(mx[hh], e);
        }
    }
#pragma unroll
    for (int hh = 0; hh < 4; ++hh)
        for (int off = 32; off; off >>= 1) mx[hh] = fmaxf(mx[hh], __shfl_xor(mx[hh], off));
    float den[4] = {0.f, 0.f, 0.f, 0.f};
    for (int j = lane; j < deg; j += 64) {
        int s = csr_src[r0 + j];
        const float4 e4 = ((const float4*)es)[s];
        const float ev[4] = {e4.x, e4.y, e4.z, e4.w};
#pragma unroll
        for (int hh = 0; hh < 4; ++hh) {
            float e = ev[hh] + edh[hh];
            e = e > 0.f ? e : 0.2f * e;
            den[hh] += __expf(e - mx[hh]);
        }
    }
#pragma unroll
    for (int hh = 0; hh < 4; ++hh) {
        for (int off = 32; off; off >>= 1) den[hh] += __shfl_xor(den[hh], off);
        den[hh] = 1.f / den[hh];
    }
    float acc[8] = {0.f, 0.f, 0.f, 0.f, 0.f, 0.f, 0.f, 0.f};
    int head = lane >> 4, c0 = (lane & 15) * 8;
    for (int base = 0; base < deg; base += 64) {
        int j = base + lane;
        if (j < deg) {
            int s = csr_src[r0 + j];
            sL[lane] = s;
            const float4 e4 = ((const float4*)es)[s];
            const float ev[4] = {e4.x, e4.y, e4.z, e4.w};
            float al[4];
#pragma unroll
            for (int hh = 0; hh < 4; ++hh) {
                float e = ev[hh] + edh[hh];
                e = e > 0.f ? e : 0.2f * e;
                al[hh] = __expf(e - mx[hh]) * den[hh];
            }
            *(float4*)&aL[lane][0] = make_float4(al[0], al[1], al[2], al[3]);
        }
        __syncthreads();
        int cnt = min(64, deg - base);
        for (int j2 = 0; j2 < cnt; ++j2) {
            int s = sL[j2];
            float al = aL[j2][head];
            u16x8 v = *(const u16x8*)&xhb[(size_t)s * 512 + head * 128 + c0];
#pragma unroll
            for (int m = 0; m < 8; ++m) acc[m] = fmaf(al, b2f(v[m]), acc[m]);
        }
        __syncthreads();
    }
#pragma unroll
    for (int m = 0; m < 8; ++m) {
        float v = acc[m];
        v += __shfl_xor(v, 16);
        v += __shfl_xor(v, 32);
        acc[m] = v;
    }
    if (lane < 16) {
        float o8[8];
        u16x8 b8;
#pragma unroll
        for (int m = 0; m < 8; ++m) {
            int c = lane * 8 + m;
            float o = acc[m] * 0.25f + bg[c];
            o = fmaxf(o, 0.f);
            float hn = h[(size_t)n * 128 + c] + o;
            o8[m] = hn;
            b8[m] = f2b(hn);
        }
        *(float4*)&h[(size_t)n * 128 + lane * 8] = make_float4(o8[0], o8[1], o8[2], o8[3]);
        *(float4*)&h[(size_t)n * 128 + lane * 8 + 4] = make_float4(o8[4], o8[5], o8[6], o8[7]);
        *(u16x8*)&hb[(size_t)n * 128 + lane * 8] = b8;
    }
}

// ================= pooling via binary search (batch sorted) =================
__global__ void pool_bs_kernel(const float* __restrict__ h, const int* __restrict__ batch,
                               u16* __restrict__ pr0b) {
    int g = blockIdx.x, t = threadIdx.x;
    int lo = 0, hi = N_NODES;
    while (lo < hi) { int m = (lo + hi) >> 1; if (batch[m] < g) lo = m + 1; else hi = m; }
    int s = lo;
    lo = 0; hi = N_NODES;
    while (lo < hi) { int m = (lo + hi) >> 1; if (batch[m] < g + 1) lo = m + 1; else hi = m; }
    int e = lo;
    float acc = 0.f;
    for (int n = s; n < e; ++n) acc += h[(size_t)n * HID + t];
    float c = fmaxf((float)(e - s), 1.f);
    pr0b[g * HID + t] = f2b(acc / c);
}

// ================= z = mu + eps * exp(0.5*logvar), dual write =================
__global__ void z_kernel(const float* __restrict__ mu, const float* __restrict__ lv,
                         const float* __restrict__ eps, float* __restrict__ z,
                         u16* __restrict__ zb) {
    int i = blockIdx.x * blockDim.x + threadIdx.x;
    if (i < N_GRAPHS * LAT) {
        float v = fmaf(eps[i], __expf(0.5f * lv[i]), mu[i]);
        z[i] = v;
        zb[i] = f2b(v);
    }
}

// ================= triu pair indices =================
__global__ void pairs_kernel(int* __restrict__ pi, int* __restrict__ pj) {
    int p = blockIdx.x * blockDim.x + threadIdx.x;
    if (p >= NPAIR) return;
    int i = 0, off = 0;
    while (off + (MAXN - 1 - i) <= p) { off += MAXN - 1 - i; ++i; }
    pi[p] = i;
    pj[p] = i + 1 + (p - off);
}

// ================= fused edge + reaction MLPs via MFMA, 64 rows per block =================
__global__ __launch_bounds__(256) void edge_react_mfma(
    const u16* __restrict__ zb, const u16* __restrict__ nb,
    const int* __restrict__ pi, const int* __restrict__ pj,
    const u16* __restrict__ We1p, const float* __restrict__ be1,
    const u16* __restrict__ We2p, const float* __restrict__ be2,
    const float* __restrict__ We3, const float* __restrict__ be3,
    const u16* __restrict__ Wr1p, const float* __restrict__ br1,
    const float* __restrict__ Wr2, const float* __restrict__ br2,
    float* __restrict__ edgep, float* __restrict__ react) {
    __shared__ u16 inA[64 * 200];
    __shared__ u16 h1A[64 * 136];
    __shared__ u16 rhA[64 * 68];
    int t = threadIdx.x, w = t >> 6, l = t & 63, lr = l & 15, lg = l >> 4;
    int b = blockIdx.y, p0 = blockIdx.x * 64;
    for (int u = t; u < 1536; u += 256) {
        int r = u / 24, c8 = (u % 24) * 8;
        int p = min(p0 + r, NPAIR - 1);
        const u16* src;
        if (c8 < 64) src = zb + b * 64 + c8;
        else if (c8 < 128) src = nb + b * NODESF + pi[p] * 64 + (c8 - 64);
        else src = nb + b * NODESF + pj[p] * 64 + (c8 - 128);
        *(u16x8*)&inA[r * 200 + c8] = *(const u16x8*)src;
    }
    __syncthreads();
    f32x4 a1[4][2];
#pragma unroll
    for (int rt = 0; rt < 4; ++rt)
#pragma unroll
        for (int ct = 0; ct < 2; ++ct) a1[rt][ct] = (f32x4){0.f, 0.f, 0.f, 0.f};
#pragma unroll
    for (int ks = 0; ks < 6; ++ks) {
        bf16x8 af[4], bf_[2];
#pragma unroll
        for (int rt = 0; rt < 4; ++rt)
            af[rt] = *(const bf16x8*)&inA[(rt * 16 + lr) * 200 + ks * 32 + lg * 8];
#pragma unroll
        for (int ct = 0; ct < 2; ++ct) {
            int col = w * 32 + ct * 16 + lr;
            bf_[ct] = *(const bf16x8*)&We1p[(size_t)((ks * 4 + lg) * 128 + col) * 8];
        }
#pragma unroll
        for (int rt = 0; rt < 4; ++rt)
#pragma unroll
            for (int ct = 0; ct < 2; ++ct)
                a1[rt][ct] = __builtin_amdgcn_mfma_f32_16x16x32_bf16(af[rt], bf_[ct], a1[rt][ct], 0, 0, 0);
    }
    f32x4 r1[4];
#pragma unroll
    for (int rt = 0; rt < 4; ++rt) r1[rt] = (f32x4){0.f, 0.f, 0.f, 0.f};
#pragma unroll
    for (int ks = 0; ks < 4; ++ks) {
        bf16x8 af[4];
#pragma unroll
        for (int rt = 0; rt < 4; ++rt)
            af[rt] = *(const bf16x8*)&inA[(rt * 16 + lr) * 200 + 64 + ks * 32 + lg * 8];
        int col = w * 16 + lr;
        bf16x8 bf_ = *(const bf16x8*)&Wr1p[(size_t)((ks * 4 + lg) * 64 + col) * 8];
#pragma unroll
        for (int rt = 0; rt < 4; ++rt)
            r1[rt] = __builtin_amdgcn_mfma_f32_16x16x32_bf16(af[rt], bf_, r1[rt], 0, 0, 0);
    }
#pragma unroll
    for (int rt = 0; rt < 4; ++rt)
#pragma unroll
        for (int ct = 0; ct < 2; ++ct) {
            int col = w * 32 + ct * 16 + lr;
            float bia = be1[col];
#pragma unroll
            for (int i = 0; i < 4; ++i) {
                int row = rt * 16 + lg * 4 + i;
                h1A[row * 136 + col] = f2b(fmaxf(a1[rt][ct][i] + bia, 0.f));
            }
        }
#pragma unroll
    for (int rt = 0; rt < 4; ++rt) {
        int col = w * 16 + lr;
        float bia = br1[col];
#pragma unroll
        for (int i = 0; i < 4; ++i) {
            int row = rt * 16 + lg * 4 + i;
            rhA[row * 68 + col] = f2b(fmaxf(r1[rt][i] + bia, 0.f));
        }
    }
    __syncthreads();
    f32x4 a2[4];
#pragma unroll
    for (int rt = 0; rt < 4; ++rt) a2[rt] = (f32x4){0.f, 0.f, 0.f, 0.f};
#pragma unroll
    for (int ks = 0; ks < 4; ++ks) {
        bf16x8 af[4];
#pragma unroll
        for (int rt = 0; rt < 4; ++rt)
            af[rt] = *(const bf16x8*)&h1A[(rt * 16 + lr) * 136 + ks * 32 + lg * 8];
        int col = w * 16 + lr;
        bf16x8 bf_ = *(const bf16x8*)&We2p[(size_t)((ks * 4 + lg) * 64 + col) * 8];
#pragma unroll
        for (int rt = 0; rt < 4; ++rt)
            a2[rt] = __builtin_amdgcn_mfma_f32_16x16x32_bf16(af[rt], bf_, a2[rt], 0, 0, 0);
    }
    u16* h2A = inA;
#pragma unroll
    for (int rt = 0; rt < 4; ++rt) {
        int col = w * 16 + lr;
        float bia = be2[col];
#pragma unroll
        for (int i = 0; i < 4; ++i) {
            int row = rt * 16 + lg * 4 + i;
            h2A[row * 68 + col] = f2b(fmaxf(a2[rt][i] + bia, 0.f));
        }
    }
    __syncthreads();
    int r = t >> 2, sub = t & 3;
    int p = p0 + r;
    float acc3 = 0.f;
#pragma unroll
    for (int kk = 0; kk < 16; ++kk) {
        int c = sub * 16 + kk;
        acc3 = fmaf(b2f(h2A[r * 68 + c]), We3[c], acc3);
    }
    acc3 += __shfl_xor(acc3, 1);
    acc3 += __shfl_xor(acc3, 2);
    if (sub == 0 && p < NPAIR)
        edgep[b * NPAIR + p] = 1.f / (1.f + __expf(-(acc3 + be3[0])));
    float lg6[6] = {0.f, 0.f, 0.f, 0.f, 0.f, 0.f};
#pragma unroll
    for (int kk = 0; kk < 16; ++kk) {
        int c = sub * 16 + kk;
        float v = b2f(rhA[r * 68 + c]);
#pragma unroll
        for (int m = 0; m < 6; ++m) lg6[m] = fmaf(v, Wr2[c * 6 + m], lg6[m]);
    }
#pragma unroll
    for (int m = 0; m < 6; ++m) {
        lg6[m] += __shfl_xor(lg6[m], 1);
        lg6[m] += __shfl_xor(lg6[m], 2);
    }
    if (sub == 0 && p < NPAIR) {
        float mx = -3.4e38f;
#pragma unroll
        for (int m = 0; m < 6; ++m) { lg6[m] += br2[m]; mx = fmaxf(mx, lg6[m]); }
        float s = 0.f;
        float ex[6];
#pragma unroll
        for (int m = 0; m < 6; ++m) { ex[m] = __expf(lg6[m] - mx); s += ex[m]; }
        float rs = 1.f / s;
#pragma unroll
        for (int m = 0; m < 6; ++m) react[(size_t)(b * NPAIR + p) * 6 + m] = ex[m] * rs;
    }
}

// ================= launch =================
extern "C" void kernel_launch(void* const* d_in, const int* in_sizes, int n_in,
                              void* d_out, int out_size, void* d_ws, size_t ws_size,
                              hipStream_t stream) {
    const float* x     = (const float*)d_in[0];
    const int*   ei    = (const int*)d_in[1];
    const int*   batch = (const int*)d_in[2];
    const float* eps   = (const float*)d_in[3];
    const float* We    = (const float*)d_in[4];
    const float* be    = (const float*)d_in[5];
    const float* Wg    = (const float*)d_in[6];
    const float* ags   = (const float*)d_in[7];
    const float* agd   = (const float*)d_in[8];
    const float* bg    = (const float*)d_in[9];
    const float* Wa1   = (const float*)d_in[10];
    const float* ba1   = (const float*)d_in[11];
    const float* Wa2   = (const float*)d_in[12];
    const float* ba2   = (const float*)d_in[13];
    const float* Wmu   = (const float*)d_in[14];
    const float* bmu   = (const float*)d_in[15];
    const float* Wlv   = (const float*)d_in[16];
    const float* blv   = (const float*)d_in[17];
    const float* Wn1   = (const float*)d_in[18];
    const float* bn1   = (const float*)d_in[19];
    const float* Wn2   = (const float*)d_in[20];
    const float* bn2   = (const float*)d_in[21];
    const float* Wn3   = (const float*)d_in[22];
    const float* bn3   = (const float*)d_in[23];
    const float* We1   = (const float*)d_in[24];
    const float* be1   = (const float*)d_in[25];
    const float* We2   = (const float*)d_in[26];
    const float* be2   = (const float*)d_in[27];
    const float* We3   = (const float*)d_in[28];
    const float* be3   = (const float*)d_in[29];
    const float* Wr1   = (const float*)d_in[30];
    const float* br1   = (const float*)d_in[31];
    const float* Wr2   = (const float*)d_in[32];
    const float* br2   = (const float*)d_in[33];

    float* out = (float*)d_out;
    float* mu_o    = out;
    float* lv_o    = out + 4096;
    float* z_o     = out + 8192;
    float* pr_o    = out + 12288;
    float* nodep_o = out + 20480;
    float* edgep_o = out + 225280;
    float* react_o = out + 303680;

    float* F = (float*)d_ws;
    size_t o = 0;
    float* h  = F + o; o += (size_t)N_NODES * HID;   // 1,280,000
    float* es = F + o; o += (size_t)N_NODES * 4;
    float* ed = F + o; o += (size_t)N_NODES * 4;
    // bf16 region (16B aligned: o*4 multiple of 16)
    u16* U = (u16*)(F + o);
    size_t uo = 0;
    u16* hb     = U + uo; uo += (size_t)N_NODES * HID;
    u16* xb     = U + uo; uo += (size_t)N_NODES * NF;
    u16* xhb    = U + uo; uo += (size_t)N_NODES * HC;
    u16* zbf    = U + uo; uo += 4096;
    u16* nbf    = U + uo; uo += 64 * NODESF;
    u16* pr0b   = U + uo; uo += 64 * HID;
    u16* t1b    = U + uo; uo += 64 * 256;
    u16* prb    = U + uo; uo += 64 * HID;
    u16* g1bb   = U + uo; uo += 64 * 256;
    u16* g2bb   = U + uo; uo += 64 * 512;
    u16* Wgp    = U + uo; uo += (size_t)3 * 16 * 512 * 8;
    u16* We1p   = U + uo; uo += 24 * 128 * 8;
    u16* We2p   = U + uo; uo += 16 * 64 * 8;
    u16* Wr1p   = U + uo; uo += 16 * 64 * 8;
    u16* Wa1p   = U + uo; uo += 16 * 256 * 8;
    u16* Wa2p   = U + uo; uo += 32 * 128 * 8;
    u16* Wmulvp = U + uo; uo += 16 * 128 * 8;
    u16* Wn1p   = U + uo; uo += 8 * 256 * 8;
    u16* Wn2p   = U + uo; uo += 32 * 512 * 8;
    u16* Wn3p   = U + uo; uo += (size_t)64 * 3200 * 8;
    u16* Wep    = U + uo; uo += 8 * 128 * 8;
    if (uo & 7) uo += 8 - (uo & 7);
    int* I = (int*)(U + uo);
    int* rowstart = I;
    int* csr_src  = I + (N_NODES + 1);
    int* piA      = I + (N_NODES + 1) + E_TOT;
    int* pjA      = piA + NPAIR;
    int* deg      = pjA + NPAIR;
    int* cursor   = deg + N_NODES;

    hipMemsetAsync(deg, 0, (size_t)N_NODES * 2 * sizeof(int), stream);

    // one mega-pack of all weights + x conversion
    PackArgs pa;
    pa.src[0] = Wg;               pa.dst[0] = Wgp;
    pa.src[1] = Wg + 65536;       pa.dst[1] = Wgp + 65536;
    pa.src[2] = Wg + 131072;      pa.dst[2] = Wgp + 131072;
    pa.src[3] = We1;              pa.dst[3] = We1p;
    pa.src[4] = We2;              pa.dst[4] = We2p;
    pa.src[5] = Wr1;              pa.dst[5] = Wr1p;
    pa.src[6] = Wa1;              pa.dst[6] = Wa1p;
    pa.src[7] = Wa2;              pa.dst[7] = Wa2p;
    pa.src[8] = Wmu;              pa.dst[8] = Wmulvp;
    pa.src[9] = Wlv;              pa.dst[9] = Wmulvp;
    pa.src[10] = Wn1;             pa.dst[10] = Wn1p;
    pa.src[11] = Wn2;             pa.dst[11] = Wn2p;
    pa.src[12] = Wn3;             pa.dst[12] = Wn3p;
    pa.src[13] = We;              pa.dst[13] = Wep;
    pa.src[14] = x;               pa.dst[14] = xb;
    pack_all_kernel<<<(PACK_TOTAL + 255) / 256, 256, 0, stream>>>(pa);

    pairs_kernel<<<5, 256, 0, stream>>>(piA, pjA);
    deg_kernel<<<(E_TOT + 255) / 256, 256, 0, stream>>>(ei, deg);
    scan_kernel<<<1, 1024, 0, stream>>>(deg, rowstart);
    fill_kernel<<<(E_TOT + 255) / 256, 256, 0, stream>>>(ei, rowstart, cursor, csr_src);

    // h = relu(x @ We + be) via MFMA, dual f32 + bf16 write
    gemm_mh_kernel<64, 128, true, true, true>
        <<<dim3((N_NODES + 63) / 64, 1), 256, 0, stream>>>(xb, Wep, be, hb, h);

    // 3 GAT layers
    for (int l = 0; l < 3; ++l) {
        gemm_mh_kernel<128, 512, false, false, false>
            <<<dim3((N_NODES + 63) / 64, 4), 256, 0, stream>>>(
                hb, Wgp + (size_t)l * 65536, nullptr, xhb, nullptr);
        esed_kernel<<<N_NODES / 4, 256, 0, stream>>>(xhb, ags + l * HC, agd + l * HC, es, ed);
        gat_agg_kernel<<<N_NODES, 64, 0, stream>>>(xhb, es, ed, rowstart, csr_src,
                                                   bg + l * HID, h, hb);
    }

    // pooling -> VAE chain (all MFMA skinny GEMMs)
    pool_bs_kernel<<<N_GRAPHS, HID, 0, stream>>>(h, batch, pr0b);
    gemm64_kernel<128, 2, 1, false><<<8, 256, 0, stream>>>(pr0b, Wa1p, ba1, nullptr, nullptr, nullptr, t1b, 256);
    gemm64_kernel<256, 4, 0, false><<<8, 256, 0, stream>>>(t1b, Wa2p, ba2, nullptr, pr_o, nullptr, prb, 128);
    gemm64_kernel<128, 2, 0, true><<<4, 256, 0, stream>>>(prb, Wmulvp, bmu, blv, mu_o, lv_o, nullptr, 128);
    z_kernel<<<16, 256, 0, stream>>>(mu_o, lv_o, eps, z_o, zbf);

    // decoder
    gemm64_kernel<64, 2, 1, false><<<8, 256, 0, stream>>>(zbf, Wn1p, bn1, nullptr, nullptr, nullptr, g1bb, 256);
    gemm64_kernel<256, 4, 1, false><<<32, 256, 0, stream>>>(g1bb, Wn2p, bn2, nullptr, nullptr, nullptr, g2bb, 512);
    gemm64_kernel<512, 4, 2, false><<<200, 256, 0, stream>>>(g2bb, Wn3p, bn3, nullptr, nodep_o, nullptr, nbf, 3200);

    // fused edge + reaction MLPs
    edge_react_mfma<<<dim3(20, 64), 256, 0, stream>>>(
        zbf, nbf, piA, pjA, We1p, be1, We2p, be2, We3, be3,
        Wr1p, br1, Wr2, br2, edgep_o, react_o);
}

// Round 5
// 259.027 us; speedup vs baseline: 2.7983x; 1.1318x over previous
//
#include <hip/hip_runtime.h>
#include <cstddef>

#define N_NODES 10000
#define N_EDGES 160000
#define E_TOT   170000
#define N_GRAPHS 64
#define NF 64
#define HID 128
#define HC 512
#define LAT 64
#define MAXN 50
#define NPAIR 1225
#define NODESF 3200

typedef __attribute__((ext_vector_type(8))) short bf16x8;
typedef __attribute__((ext_vector_type(8))) unsigned short u16x8;
typedef __attribute__((ext_vector_type(4))) float f32x4;
typedef unsigned short u16;
typedef unsigned int u32;

__device__ __forceinline__ u16 f2b(float f) {
    u32 u = __float_as_uint(f);
    u32 r = (u + 0x7fffu + ((u >> 16) & 1u)) >> 16;
    return (u16)r;
}
__device__ __forceinline__ float b2f(u16 v) {
    return __uint_as_float(((u32)v) << 16);
}

// ================= pack_all: every weight -> bf16 B-fragment layout, + x -> bf16 =================
struct PackArgs {
    const float* src[15];
    u16* dst[15];
};
#define PACK_TOTAL 344192
__global__ void pack_all_kernel(PackArgs pa) {
    int idx = blockIdx.x * 256 + threadIdx.x;
    if (idx >= PACK_TOTAL) return;
    const int base[16] = {0, 8192, 16384, 24576, 27648, 28672, 29696, 33792, 37888,
                          38912, 39936, 41984, 58368, 263168, 264192, 344192};
    const int Ns[15]   = {512, 512, 512, 128, 64, 64, 256, 128, 64, 64, 256, 512, 3200, 128, 0};
    const int dNs[15]  = {512, 512, 512, 128, 64, 64, 256, 128, 128, 128, 256, 512, 3200, 128, 0};
    const int coff[15] = {0, 0, 0, 0, 0, 0, 0, 0, 0, 64, 0, 0, 0, 0, 0};
    int s = 0;
    while (idx >= base[s + 1]) ++s;
    int i = idx - base[s];
    const float* sp = pa.src[s];
    u16* dp = pa.dst[s];
    if (s == 14) {
        u16x8 o;
#pragma unroll
        for (int j = 0; j < 8; ++j) o[j] = f2b(sp[(size_t)i * 8 + j]);
        *(u16x8*)&dp[(size_t)i * 8] = o;
        return;
    }
    int N = Ns[s];
    int g = i / N, n = i - g * N;
    u16x8 o;
#pragma unroll
    for (int j = 0; j < 8; ++j) o[j] = f2b(sp[(size_t)(g * 8 + j) * N + n]);
    *(u16x8*)&dp[((size_t)g * dNs[s] + n + coff[s]) * 8] = o;
}

// ================= CSR build =================
__global__ void deg_kernel(const int* __restrict__ ei, int* __restrict__ deg) {
    int e = blockIdx.x * blockDim.x + threadIdx.x;
    if (e >= E_TOT) return;
    int d = (e < N_EDGES) ? ei[N_EDGES + e] : (e - N_EDGES);
    atomicAdd(&deg[d], 1);
}

__global__ void scan_kernel(const int* __restrict__ deg, int* __restrict__ rowstart) {
    __shared__ int wsum[16];
    __shared__ int carry_s;
    int lane = threadIdx.x & 63, wv = threadIdx.x >> 6;
    if (threadIdx.x == 0) carry_s = 0;
    __syncthreads();
    for (int base = 0; base < N_NODES; base += 1024) {
        int i = base + (int)threadIdx.x;
        int v = (i < N_NODES) ? deg[i] : 0;
        int s = v;
#pragma unroll
        for (int d = 1; d < 64; d <<= 1) {
            int u = __shfl_up(s, d);
            if (lane >= d) s += u;
        }
        if (lane == 63) wsum[wv] = s;
        __syncthreads();
        if (wv == 0 && lane < 16) {
            int ws = wsum[lane];
            int t2 = ws;
#pragma unroll
            for (int d = 1; d < 16; d <<= 1) {
                int u = __shfl_up(t2, d);
                if (lane >= d) t2 += u;
            }
            wsum[lane] = t2 - ws;
        }
        __syncthreads();
        int incl = s + wsum[wv] + carry_s;
        if (i < N_NODES) rowstart[i] = incl - v;
        __syncthreads();
        if (threadIdx.x == 1023) carry_s = incl;
        __syncthreads();
    }
    if (threadIdx.x == 0) rowstart[N_NODES] = carry_s;
}

__global__ void fill_kernel(const int* __restrict__ ei, const int* __restrict__ rowstart,
                            int* __restrict__ cursor, int* __restrict__ csr_src) {
    int e = blockIdx.x * blockDim.x + threadIdx.x;
    if (e >= E_TOT) return;
    int s, d;
    if (e < N_EDGES) { s = ei[e]; d = ei[N_EDGES + e]; }
    else { s = e - N_EDGES; d = s; }
    int pos = atomicAdd(&cursor[d], 1);
    csr_src[rowstart[d] + pos] = s;
}

// ================= gemm_mh: M-large MFMA GEMM, 64 rows x 128 cols per block =================
template<int K, int NT, bool BIAS, bool RELU, bool F32OUT>
__global__ __launch_bounds__(256) void gemm_mh_kernel(const u16* __restrict__ A,
                                                      const u16* __restrict__ Wp,
                                                      const float* __restrict__ bias,
                                                      u16* __restrict__ bo,
                                                      float* __restrict__ fo) {
    __shared__ u16 AL[64 * (K + 8)];
    int t = threadIdx.x, w = t >> 6, l = t & 63, lr = l & 15, lg = l >> 4;
    int rb = blockIdx.x * 64, j0 = blockIdx.y * 128;
    for (int u = t; u < 64 * (K / 8); u += 256) {
        int r = u / (K / 8), c8 = (u % (K / 8)) * 8;
        int row = min(rb + r, N_NODES - 1);
        *(u16x8*)&AL[r * (K + 8) + c8] = *(const u16x8*)&A[(size_t)row * K + c8];
    }
    __syncthreads();
    f32x4 acc[4][2];
#pragma unroll
    for (int rt = 0; rt < 4; ++rt)
#pragma unroll
        for (int ct = 0; ct < 2; ++ct) acc[rt][ct] = (f32x4){0.f, 0.f, 0.f, 0.f};
#pragma unroll
    for (int ks = 0; ks < K / 32; ++ks) {
        bf16x8 a[4], b[2];
#pragma unroll
        for (int rt = 0; rt < 4; ++rt)
            a[rt] = *(const bf16x8*)&AL[(rt * 16 + lr) * (K + 8) + ks * 32 + lg * 8];
#pragma unroll
        for (int ct = 0; ct < 2; ++ct) {
            int col = j0 + w * 32 + ct * 16 + lr;
            b[ct] = *(const bf16x8*)&Wp[(size_t)((ks * 4 + lg) * NT + col) * 8];
        }
#pragma unroll
        for (int rt = 0; rt < 4; ++rt)
#pragma unroll
            for (int ct = 0; ct < 2; ++ct)
                acc[rt][ct] = __builtin_amdgcn_mfma_f32_16x16x32_bf16(a[rt], b[ct], acc[rt][ct], 0, 0, 0);
    }
#pragma unroll
    for (int rt = 0; rt < 4; ++rt)
#pragma unroll
        for (int ct = 0; ct < 2; ++ct) {
            int col = j0 + w * 32 + ct * 16 + lr;
            float bj = BIAS ? bias[col] : 0.f;
#pragma unroll
            for (int i = 0; i < 4; ++i) {
                int row = rb + rt * 16 + lg * 4 + i;
                if (row < N_NODES) {
                    float v = acc[rt][ct][i] + bj;
                    if (RELU) v = fmaxf(v, 0.f);
                    bo[(size_t)row * NT + col] = f2b(v);
                    if (F32OUT) fo[(size_t)row * NT + col] = v;
                }
            }
        }
}

// ================= gemm64: M=64 skinny MFMA GEMM with intra-block split-K =================
// ACT: 0 none, 1 relu, 2 sigmoid->fo & raw bf16->bo.
template<int K, int G, int ACT, bool SPLIT>
__global__ __launch_bounds__(256) void gemm64_kernel(const u16* __restrict__ A,
                                                     const u16* __restrict__ Wp,
                                                     const float* __restrict__ bias,
                                                     const float* __restrict__ bias2,
                                                     float* __restrict__ fo,
                                                     float* __restrict__ fo2,
                                                     u16* __restrict__ bo, int N) {
    constexpr int CG = 4 / G, NB = CG * 16, Kc = K / G, KS = Kc / 32;
    constexpr int ABYTES = 64 * (K + 8) * 2;
    constexpr int LDSB = (ABYTES > 16384) ? ABYTES : 16384;
    __shared__ float LDSf[LDSB / 4];
    u16* AL = (u16*)LDSf;
    float* RB = LDSf;
    int t = threadIdx.x, w = t >> 6, l = t & 63, lr = l & 15, lg = l >> 4;
    for (int u = t; u < 64 * (K / 8); u += 256) {
        int r = u / (K / 8), c8 = (u % (K / 8)) * 8;
        *(u16x8*)&AL[r * (K + 8) + c8] = *(const u16x8*)&A[(size_t)r * K + c8];
    }
    __syncthreads();
    int kg = w % G, cg = w / G;
    int col = blockIdx.x * NB + cg * 16 + lr;
    f32x4 acc[4];
#pragma unroll
    for (int rt = 0; rt < 4; ++rt) acc[rt] = (f32x4){0.f, 0.f, 0.f, 0.f};
#pragma unroll
    for (int ks = 0; ks < KS; ++ks) {
        int k0 = kg * Kc + ks * 32;
        bf16x8 b = *(const bf16x8*)&Wp[(size_t)(((k0 >> 3) + lg) * N + col) * 8];
#pragma unroll
        for (int rt = 0; rt < 4; ++rt) {
            bf16x8 a = *(const bf16x8*)&AL[(rt * 16 + lr) * (K + 8) + k0 + lg * 8];
            acc[rt] = __builtin_amdgcn_mfma_f32_16x16x32_bf16(a, b, acc[rt], 0, 0, 0);
        }
    }
    __syncthreads();
#pragma unroll
    for (int rt = 0; rt < 4; ++rt)
#pragma unroll
        for (int i = 0; i < 4; ++i)
            RB[w * 1024 + (rt * 16 + lg * 4 + i) * 16 + lr] = acc[rt][i];
    __syncthreads();
    for (int e = t; e < 64 * NB; e += 256) {
        int row = e / NB, cb = e - row * NB;
        int cg2 = cb >> 4, cl = cb & 15;
        float s = 0.f;
#pragma unroll
        for (int kg2 = 0; kg2 < G; ++kg2)
            s += RB[(cg2 * G + kg2) * 1024 + row * 16 + cl];
        int c = blockIdx.x * NB + cb;
        float bj;
        if (SPLIT) bj = (c < 64) ? bias[c] : bias2[c - 64];
        else bj = bias[c];
        float v = s + bj;
        if (ACT == 1) v = fmaxf(v, 0.f);
        if (bo) bo[(size_t)row * N + c] = f2b(v);
        if (SPLIT) {
            if (c < 64) fo[row * 64 + c] = v;
            else fo2[row * 64 + (c - 64)] = v;
        } else if (fo) {
            float ov = (ACT == 2) ? 1.f / (1.f + __expf(-v)) : v;
            fo[(size_t)row * N + c] = ov;
        }
    }
}

// ================= mm64: in-kernel M=64 MFMA sub-GEMM (4 waves, N/64 col passes) =================
template<int K, int N, typename EP>
__device__ __forceinline__ void mm64(const u16* __restrict__ AL, int lda,
                                     const u16* __restrict__ Wp, EP ep) {
    int t = threadIdx.x, w = t >> 6, l = t & 63, lr = l & 15, lg = l >> 4;
#pragma unroll
    for (int p = 0; p < N / 64; ++p) {
        int col = p * 64 + w * 16 + lr;
        f32x4 acc[4];
#pragma unroll
        for (int rt = 0; rt < 4; ++rt) acc[rt] = (f32x4){0.f, 0.f, 0.f, 0.f};
#pragma unroll
        for (int ks = 0; ks < K / 32; ++ks) {
            bf16x8 b = *(const bf16x8*)&Wp[(size_t)((ks * 4 + lg) * N + col) * 8];
#pragma unroll
            for (int rt = 0; rt < 4; ++rt) {
                bf16x8 a = *(const bf16x8*)&AL[(rt * 16 + lr) * lda + ks * 32 + lg * 8];
                acc[rt] = __builtin_amdgcn_mfma_f32_16x16x32_bf16(a, b, acc[rt], 0, 0, 0);
            }
        }
#pragma unroll
        for (int rt = 0; rt < 4; ++rt)
#pragma unroll
            for (int i = 0; i < 4; ++i)
                ep(rt * 16 + lg * 4 + i, col, acc[rt][i]);
    }
}

// ================= fused VAE chain: pr0 -> Wa1 -> Wa2 -> mu/lv -> z -> Wn1 -> Wn2, 1 block =================
__global__ __launch_bounds__(256) void fused_vae_kernel(
    const u16* __restrict__ pr0b, const float* __restrict__ eps,
    const u16* __restrict__ Wa1p, const float* __restrict__ ba1,
    const u16* __restrict__ Wa2p, const float* __restrict__ ba2,
    const u16* __restrict__ Wmulvp, const float* __restrict__ bmu, const float* __restrict__ blv,
    const u16* __restrict__ Wn1p, const float* __restrict__ bn1,
    const u16* __restrict__ Wn2p, const float* __restrict__ bn2,
    float* __restrict__ pr_o, float* __restrict__ mu_o, float* __restrict__ lv_o,
    float* __restrict__ z_o, u16* __restrict__ zbf, u16* __restrict__ g2bb) {
    __shared__ u16 P[64 * 136];   // 17.4 KB: pr0, then pr
    __shared__ u16 T[64 * 272];   // 34.8 KB: t1, then MVf (f32), then g1
    __shared__ u16 Z[64 * 72];    //  9.2 KB: z
    float* MVf = (float*)T;
    int t = threadIdx.x;
    // S0: load pooled pr0 (bf16)
    for (int idx = t; idx < 8192; idx += 256) {
        int g = idx >> 7, c = idx & 127;
        P[g * 136 + c] = pr0b[idx];
    }
    __syncthreads();
    // S1: t1 = relu(pr0 @ Wa1 + ba1)   [K=128 -> N=256]
    mm64<128, 256>(P, 136, Wa1p, [&](int row, int col, float v) {
        T[row * 272 + col] = f2b(fmaxf(v + ba1[col], 0.f));
    });
    __syncthreads();
    // S2: pr = t1 @ Wa2 + ba2          [K=256 -> N=128]
    mm64<256, 128>(T, 272, Wa2p, [&](int row, int col, float v) {
        v += ba2[col];
        pr_o[row * 128 + col] = v;
        P[row * 136 + col] = f2b(v);
    });
    __syncthreads();
    // S3: [mu | lv] = pr @ Wmulv + b   [K=128 -> N=128]
    mm64<128, 128>(P, 136, Wmulvp, [&](int row, int col, float v) {
        v += (col < 64) ? bmu[col] : blv[col - 64];
        MVf[row * 136 + col] = v;
        if (col < 64) mu_o[row * 64 + col] = v;
        else lv_o[row * 64 + (col - 64)] = v;
    });
    __syncthreads();
    // S4: z = mu + eps * exp(0.5*lv)
    for (int idx = t; idx < 4096; idx += 256) {
        int g = idx >> 6, c = idx & 63;
        float m = MVf[g * 136 + c], lvv = MVf[g * 136 + 64 + c];
        float zv = fmaf(eps[idx], __expf(0.5f * lvv), m);
        z_o[idx] = zv;
        u16 zb16 = f2b(zv);
        zbf[idx] = zb16;
        Z[g * 72 + c] = zb16;
    }
    __syncthreads();
    // S5: g1 = relu(z @ Wn1 + bn1)     [K=64 -> N=256]
    mm64<64, 256>(Z, 72, Wn1p, [&](int row, int col, float v) {
        T[row * 272 + col] = f2b(fmaxf(v + bn1[col], 0.f));
    });
    __syncthreads();
    // S6: g2 = relu(g1 @ Wn2 + bn2)    [K=256 -> N=512] -> global bf16
    mm64<256, 512>(T, 272, Wn2p, [&](int row, int col, float v) {
        g2bb[row * 512 + col] = f2b(fmaxf(v + bn2[col], 0.f));
    });
}

// ================= es/ed from bf16 xh =================
__global__ void esed_kernel(const u16* __restrict__ xhb, const float* __restrict__ ags,
                            const float* __restrict__ agd, float* __restrict__ es,
                            float* __restrict__ ed) {
    int wv = threadIdx.x >> 6, lane = threadIdx.x & 63;
    int n = blockIdx.x * 4 + wv;
    if (n >= N_NODES) return;
    u16x8 v = *(const u16x8*)&xhb[(size_t)n * 512 + lane * 8];
    float ps = 0.f, pd = 0.f;
#pragma unroll
    for (int j = 0; j < 8; ++j) {
        float f = b2f(v[j]);
        ps = fmaf(f, ags[lane * 8 + j], ps);
        pd = fmaf(f, agd[lane * 8 + j], pd);
    }
#pragma unroll
    for (int off = 1; off < 16; off <<= 1) {
        ps += __shfl_xor(ps, off);
        pd += __shfl_xor(pd, off);
    }
    if ((lane & 15) == 0) {
        es[n * 4 + (lane >> 4)] = ps;
        ed[n * 4 + (lane >> 4)] = pd;
    }
}

// ================= GAT aggregation: one wave per dst node =================
__global__ __launch_bounds__(64) void gat_agg_kernel(const u16* __restrict__ xhb,
                               const float* __restrict__ es, const float* __restrict__ ed,
                               const int* __restrict__ rowstart, const int* __restrict__ csr_src,
                               const float* __restrict__ bg, float* __restrict__ h,
                               u16* __restrict__ hb) {
    __shared__ float aL[64][4];
    __shared__ int sL[64];
    int n = blockIdx.x;
    int lane = threadIdx.x;
    int r0 = rowstart[n], r1 = rowstart[n + 1];
    int deg = r1 - r0;
    const float4 ed4 = ((const float4*)ed)[n];
    const float edh[4] = {ed4.x, ed4.y, ed4.z, ed4.w};
    float mx[4] = {-3.4e38f, -3.4e38f, -3.4e38f, -3.4e38f};
    for (int j = lane; j < deg; j += 64) {
        int s = csr_src[r0 + j];
        const float4 e4 = ((const float4*)es)[s];
        const float ev[4] = {e4.x, e4.y, e4.z, e4.w};
#pragma unroll
        for (int hh = 0; hh < 4; ++hh) {
            float e = ev[hh] + edh[hh];
            e = e > 0.f ? e : 0.2f * e;
            mx[hh] = fmaxf(mx[hh], e);
        }
    }
#pragma unroll
    for (int hh = 0; hh < 4; ++hh)
        for (int off = 32; off; off >>= 1) mx[hh] = fmaxf(mx[hh], __shfl_xor(mx[hh], off));
    float den[4] = {0.f, 0.f, 0.f, 0.f};
    for (int j = lane; j < deg; j += 64) {
        int s = csr_src[r0 + j];
        const float4 e4 = ((const float4*)es)[s];
        const float ev[4] = {e4.x, e4.y, e4.z, e4.w};
#pragma unroll
        for (int hh = 0; hh < 4; ++hh) {
            float e = ev[hh] + edh[hh];
            e = e > 0.f ? e : 0.2f * e;
            den[hh] += __expf(e - mx[hh]);
        }
    }
#pragma unroll
    for (int hh = 0; hh < 4; ++hh) {
        for (int off = 32; off; off >>= 1) den[hh] += __shfl_xor(den[hh], off);
        den[hh] = 1.f / den[hh];
    }
    float acc[8] = {0.f, 0.f, 0.f, 0.f, 0.f, 0.f, 0.f, 0.f};
    int head = lane >> 4, c0 = (lane & 15) * 8;
    for (int base = 0; base < deg; base += 64) {
        int j = base + lane;
        if (j < deg) {
            int s = csr_src[r0 + j];
            sL[lane] = s;
            const float4 e4 = ((const float4*)es)[s];
            const float ev[4] = {e4.x, e4.y, e4.z, e4.w};
            float al[4];
#pragma unroll
            for (int hh = 0; hh < 4; ++hh) {
                float e = ev[hh] + edh[hh];
                e = e > 0.f ? e : 0.2f * e;
                al[hh] = __expf(e - mx[hh]) * den[hh];
            }
            *(float4*)&aL[lane][0] = make_float4(al[0], al[1], al[2], al[3]);
        }
        __syncthreads();
        int cnt = min(64, deg - base);
        for (int j2 = 0; j2 < cnt; ++j2) {
            int s = sL[j2];
            float al = aL[j2][head];
            u16x8 v = *(const u16x8*)&xhb[(size_t)s * 512 + head * 128 + c0];
#pragma unroll
            for (int m = 0; m < 8; ++m) acc[m] = fmaf(al, b2f(v[m]), acc[m]);
        }
        __syncthreads();
    }
#pragma unroll
    for (int m = 0; m < 8; ++m) {
        float v = acc[m];
        v += __shfl_xor(v, 16);
        v += __shfl_xor(v, 32);
        acc[m] = v;
    }
    if (lane < 16) {
        float o8[8];
        u16x8 b8;
#pragma unroll
        for (int m = 0; m < 8; ++m) {
            int c = lane * 8 + m;
            float o = acc[m] * 0.25f + bg[c];
            o = fmaxf(o, 0.f);
            float hn = h[(size_t)n * 128 + c] + o;
            o8[m] = hn;
            b8[m] = f2b(hn);
        }
        *(float4*)&h[(size_t)n * 128 + lane * 8] = make_float4(o8[0], o8[1], o8[2], o8[3]);
        *(float4*)&h[(size_t)n * 128 + lane * 8 + 4] = make_float4(o8[4], o8[5], o8[6], o8[7]);
        *(u16x8*)&hb[(size_t)n * 128 + lane * 8] = b8;
    }
}

// ================= pooling: one block per graph, 1024 threads (8 row-groups x 128 cols) =================
__global__ __launch_bounds__(1024) void pool_kernel2(const float* __restrict__ h,
                                                     const int* __restrict__ batch,
                                                     u16* __restrict__ pr0b) {
    __shared__ float red[8][128];
    int g = blockIdx.x;
    int t = threadIdx.x;
    int c = t & 127, rg = t >> 7;
    int lo = 0, hi = N_NODES;
    while (lo < hi) { int m = (lo + hi) >> 1; if (batch[m] < g) lo = m + 1; else hi = m; }
    int s = lo;
    lo = 0; hi = N_NODES;
    while (lo < hi) { int m = (lo + hi) >> 1; if (batch[m] < g + 1) lo = m + 1; else hi = m; }
    int e = lo;
    float acc = 0.f;
    for (int n = s + rg; n < e; n += 8) acc += h[(size_t)n * HID + c];
    red[rg][c] = acc;
    __syncthreads();
    if (rg == 0) {
        float sum = ((red[0][c] + red[1][c]) + (red[2][c] + red[3][c])) +
                    ((red[4][c] + red[5][c]) + (red[6][c] + red[7][c]));
        float cn = fmaxf((float)(e - s), 1.f);
        pr0b[g * HID + c] = f2b(sum / cn);
    }
}

// ================= triu pair indices =================
__global__ void pairs_kernel(int* __restrict__ pi, int* __restrict__ pj) {
    int p = blockIdx.x * blockDim.x + threadIdx.x;
    if (p >= NPAIR) return;
    int i = 0, off = 0;
    while (off + (MAXN - 1 - i) <= p) { off += MAXN - 1 - i; ++i; }
    pi[p] = i;
    pj[p] = i + 1 + (p - off);
}

// ================= fused edge + reaction MLPs via MFMA, 64 rows per block =================
__global__ __launch_bounds__(256) void edge_react_mfma(
    const u16* __restrict__ zb, const u16* __restrict__ nb,
    const int* __restrict__ pi, const int* __restrict__ pj,
    const u16* __restrict__ We1p, const float* __restrict__ be1,
    const u16* __restrict__ We2p, const float* __restrict__ be2,
    const float* __restrict__ We3, const float* __restrict__ be3,
    const u16* __restrict__ Wr1p, const float* __restrict__ br1,
    const float* __restrict__ Wr2, const float* __restrict__ br2,
    float* __restrict__ edgep, float* __restrict__ react) {
    __shared__ u16 inA[64 * 200];
    __shared__ u16 h1A[64 * 136];
    __shared__ u16 rhA[64 * 68];
    int t = threadIdx.x, w = t >> 6, l = t & 63, lr = l & 15, lg = l >> 4;
    int b = blockIdx.y, p0 = blockIdx.x * 64;
    for (int u = t; u < 1536; u += 256) {
        int r = u / 24, c8 = (u % 24) * 8;
        int p = min(p0 + r, NPAIR - 1);
        const u16* src;
        if (c8 < 64) src = zb + b * 64 + c8;
        else if (c8 < 128) src = nb + b * NODESF + pi[p] * 64 + (c8 - 64);
        else src = nb + b * NODESF + pj[p] * 64 + (c8 - 128);
        *(u16x8*)&inA[r * 200 + c8] = *(const u16x8*)src;
    }
    __syncthreads();
    f32x4 a1[4][2];
#pragma unroll
    for (int rt = 0; rt < 4; ++rt)
#pragma unroll
        for (int ct = 0; ct < 2; ++ct) a1[rt][ct] = (f32x4){0.f, 0.f, 0.f, 0.f};
#pragma unroll
    for (int ks = 0; ks < 6; ++ks) {
        bf16x8 af[4], bf_[2];
#pragma unroll
        for (int rt = 0; rt < 4; ++rt)
            af[rt] = *(const bf16x8*)&inA[(rt * 16 + lr) * 200 + ks * 32 + lg * 8];
#pragma unroll
        for (int ct = 0; ct < 2; ++ct) {
            int col = w * 32 + ct * 16 + lr;
            bf_[ct] = *(const bf16x8*)&We1p[(size_t)((ks * 4 + lg) * 128 + col) * 8];
        }
#pragma unroll
        for (int rt = 0; rt < 4; ++rt)
#pragma unroll
            for (int ct = 0; ct < 2; ++ct)
                a1[rt][ct] = __builtin_amdgcn_mfma_f32_16x16x32_bf16(af[rt], bf_[ct], a1[rt][ct], 0, 0, 0);
    }
    f32x4 r1[4];
#pragma unroll
    for (int rt = 0; rt < 4; ++rt) r1[rt] = (f32x4){0.f, 0.f, 0.f, 0.f};
#pragma unroll
    for (int ks = 0; ks < 4; ++ks) {
        bf16x8 af[4];
#pragma unroll
        for (int rt = 0; rt < 4; ++rt)
            af[rt] = *(const bf16x8*)&inA[(rt * 16 + lr) * 200 + 64 + ks * 32 + lg * 8];
        int col = w * 16 + lr;
        bf16x8 bf_ = *(const bf16x8*)&Wr1p[(size_t)((ks * 4 + lg) * 64 + col) * 8];
#pragma unroll
        for (int rt = 0; rt < 4; ++rt)
            r1[rt] = __builtin_amdgcn_mfma_f32_16x16x32_bf16(af[rt], bf_, r1[rt], 0, 0, 0);
    }
#pragma unroll
    for (int rt = 0; rt < 4; ++rt)
#pragma unroll
        for (int ct = 0; ct < 2; ++ct) {
            int col = w * 32 + ct * 16 + lr;
            float bia = be1[col];
#pragma unroll
            for (int i = 0; i < 4; ++i) {
                int row = rt * 16 + lg * 4 + i;
                h1A[row * 136 + col] = f2b(fmaxf(a1[rt][ct][i] + bia, 0.f));
            }
        }
#pragma unroll
    for (int rt = 0; rt < 4; ++rt) {
        int col = w * 16 + lr;
        float bia = br1[col];
#pragma unroll
        for (int i = 0; i < 4; ++i) {
            int row = rt * 16 + lg * 4 + i;
            rhA[row * 68 + col] = f2b(fmaxf(r1[rt][i] + bia, 0.f));
        }
    }
    __syncthreads();
    f32x4 a2[4];
#pragma unroll
    for (int rt = 0; rt < 4; ++rt) a2[rt] = (f32x4){0.f, 0.f, 0.f, 0.f};
#pragma unroll
    for (int ks = 0; ks < 4; ++ks) {
        bf16x8 af[4];
#pragma unroll
        for (int rt = 0; rt < 4; ++rt)
            af[rt] = *(const bf16x8*)&h1A[(rt * 16 + lr) * 136 + ks * 32 + lg * 8];
        int col = w * 16 + lr;
        bf16x8 bf_ = *(const bf16x8*)&We2p[(size_t)((ks * 4 + lg) * 64 + col) * 8];
#pragma unroll
        for (int rt = 0; rt < 4; ++rt)
            a2[rt] = __builtin_amdgcn_mfma_f32_16x16x32_bf16(af[rt], bf_, a2[rt], 0, 0, 0);
    }
    u16* h2A = inA;
#pragma unroll
    for (int rt = 0; rt < 4; ++rt) {
        int col = w * 16 + lr;
        float bia = be2[col];
#pragma unroll
        for (int i = 0; i < 4; ++i) {
            int row = rt * 16 + lg * 4 + i;
            h2A[row * 68 + col] = f2b(fmaxf(a2[rt][i] + bia, 0.f));
        }
    }
    __syncthreads();
    int r = t >> 2, sub = t & 3;
    int p = p0 + r;
    float acc3 = 0.f;
#pragma unroll
    for (int kk = 0; kk < 16; ++kk) {
        int c = sub * 16 + kk;
        acc3 = fmaf(b2f(h2A[r * 68 + c]), We3[c], acc3);
    }
    acc3 += __shfl_xor(acc3, 1);
    acc3 += __shfl_xor(acc3, 2);
    if (sub == 0 && p < NPAIR)
        edgep[b * NPAIR + p] = 1.f / (1.f + __expf(-(acc3 + be3[0])));
    float lg6[6] = {0.f, 0.f, 0.f, 0.f, 0.f, 0.f};
#pragma unroll
    for (int kk = 0; kk < 16; ++kk) {
        int c = sub * 16 + kk;
        float v = b2f(rhA[r * 68 + c]);
#pragma unroll
        for (int m = 0; m < 6; ++m) lg6[m] = fmaf(v, Wr2[c * 6 + m], lg6[m]);
    }
#pragma unroll
    for (int m = 0; m < 6; ++m) {
        lg6[m] += __shfl_xor(lg6[m], 1);
        lg6[m] += __shfl_xor(lg6[m], 2);
    }
    if (sub == 0 && p < NPAIR) {
        float mx = -3.4e38f;
#pragma unroll
        for (int m = 0; m < 6; ++m) { lg6[m] += br2[m]; mx = fmaxf(mx, lg6[m]); }
        float s = 0.f;
        float ex[6];
#pragma unroll
        for (int m = 0; m < 6; ++m) { ex[m] = __expf(lg6[m] - mx); s += ex[m]; }
        float rs = 1.f / s;
#pragma unroll
        for (int m = 0; m < 6; ++m) react[(size_t)(b * NPAIR + p) * 6 + m] = ex[m] * rs;
    }
}

// ================= launch =================
extern "C" void kernel_launch(void* const* d_in, const int* in_sizes, int n_in,
                              void* d_out, int out_size, void* d_ws, size_t ws_size,
                              hipStream_t stream) {
    const float* x     = (const float*)d_in[0];
    const int*   ei    = (const int*)d_in[1];
    const int*   batch = (const int*)d_in[2];
    const float* eps   = (const float*)d_in[3];
    const float* We    = (const float*)d_in[4];
    const float* be    = (const float*)d_in[5];
    const float* Wg    = (const float*)d_in[6];
    const float* ags   = (const float*)d_in[7];
    const float* agd   = (const float*)d_in[8];
    const float* bg    = (const float*)d_in[9];
    const float* Wa1   = (const float*)d_in[10];
    const float* ba1   = (const float*)d_in[11];
    const float* Wa2   = (const float*)d_in[12];
    const float* ba2   = (const float*)d_in[13];
    const float* Wmu   = (const float*)d_in[14];
    const float* bmu   = (const float*)d_in[15];
    const float* Wlv   = (const float*)d_in[16];
    const float* blv   = (const float*)d_in[17];
    const float* Wn1   = (const float*)d_in[18];
    const float* bn1   = (const float*)d_in[19];
    const float* Wn2   = (const float*)d_in[20];
    const float* bn2   = (const float*)d_in[21];
    const float* Wn3   = (const float*)d_in[22];
    const float* bn3   = (const float*)d_in[23];
    const float* We1   = (const float*)d_in[24];
    const float* be1   = (const float*)d_in[25];
    const float* We2   = (const float*)d_in[26];
    const float* be2   = (const float*)d_in[27];
    const float* We3   = (const float*)d_in[28];
    const float* be3   = (const float*)d_in[29];
    const float* Wr1   = (const float*)d_in[30];
    const float* br1   = (const float*)d_in[31];
    const float* Wr2   = (const float*)d_in[32];
    const float* br2   = (const float*)d_in[33];

    float* out = (float*)d_out;
    float* mu_o    = out;
    float* lv_o    = out + 4096;
    float* z_o     = out + 8192;
    float* pr_o    = out + 12288;
    float* nodep_o = out + 20480;
    float* edgep_o = out + 225280;
    float* react_o = out + 303680;

    float* F = (float*)d_ws;
    size_t o = 0;
    float* h  = F + o; o += (size_t)N_NODES * HID;
    float* es = F + o; o += (size_t)N_NODES * 4;
    float* ed = F + o; o += (size_t)N_NODES * 4;
    u16* U = (u16*)(F + o);
    size_t uo = 0;
    u16* hb     = U + uo; uo += (size_t)N_NODES * HID;
    u16* xb     = U + uo; uo += (size_t)N_NODES * NF;
    u16* xhb    = U + uo; uo += (size_t)N_NODES * HC;
    u16* zbf    = U + uo; uo += 4096;
    u16* nbf    = U + uo; uo += 64 * NODESF;
    u16* pr0b   = U + uo; uo += 64 * HID;
    u16* g2bb   = U + uo; uo += 64 * 512;
    u16* Wgp    = U + uo; uo += (size_t)3 * 16 * 512 * 8;
    u16* We1p   = U + uo; uo += 24 * 128 * 8;
    u16* We2p   = U + uo; uo += 16 * 64 * 8;
    u16* Wr1p   = U + uo; uo += 16 * 64 * 8;
    u16* Wa1p   = U + uo; uo += 16 * 256 * 8;
    u16* Wa2p   = U + uo; uo += 32 * 128 * 8;
    u16* Wmulvp = U + uo; uo += 16 * 128 * 8;
    u16* Wn1p   = U + uo; uo += 8 * 256 * 8;
    u16* Wn2p   = U + uo; uo += 32 * 512 * 8;
    u16* Wn3p   = U + uo; uo += (size_t)64 * 3200 * 8;
    u16* Wep    = U + uo; uo += 8 * 128 * 8;
    if (uo & 7) uo += 8 - (uo & 7);
    int* I = (int*)(U + uo);
    int* rowstart = I;
    int* csr_src  = I + (N_NODES + 1);
    int* piA      = I + (N_NODES + 1) + E_TOT;
    int* pjA      = piA + NPAIR;
    int* deg      = pjA + NPAIR;
    int* cursor   = deg + N_NODES;

    hipMemsetAsync(deg, 0, (size_t)N_NODES * 2 * sizeof(int), stream);

    PackArgs pa;
    pa.src[0] = Wg;               pa.dst[0] = Wgp;
    pa.src[1] = Wg + 65536;       pa.dst[1] = Wgp + 65536;
    pa.src[2] = Wg + 131072;      pa.dst[2] = Wgp + 131072;
    pa.src[3] = We1;              pa.dst[3] = We1p;
    pa.src[4] = We2;              pa.dst[4] = We2p;
    pa.src[5] = Wr1;              pa.dst[5] = Wr1p;
    pa.src[6] = Wa1;              pa.dst[6] = Wa1p;
    pa.src[7] = Wa2;              pa.dst[7] = Wa2p;
    pa.src[8] = Wmu;              pa.dst[8] = Wmulvp;
    pa.src[9] = Wlv;              pa.dst[9] = Wmulvp;
    pa.src[10] = Wn1;             pa.dst[10] = Wn1p;
    pa.src[11] = Wn2;             pa.dst[11] = Wn2p;
    pa.src[12] = Wn3;             pa.dst[12] = Wn3p;
    pa.src[13] = We;              pa.dst[13] = Wep;
    pa.src[14] = x;               pa.dst[14] = xb;
    pack_all_kernel<<<(PACK_TOTAL + 255) / 256, 256, 0, stream>>>(pa);

    pairs_kernel<<<5, 256, 0, stream>>>(piA, pjA);
    deg_kernel<<<(E_TOT + 255) / 256, 256, 0, stream>>>(ei, deg);
    scan_kernel<<<1, 1024, 0, stream>>>(deg, rowstart);
    fill_kernel<<<(E_TOT + 255) / 256, 256, 0, stream>>>(ei, rowstart, cursor, csr_src);

    // h = relu(x @ We + be)
    gemm_mh_kernel<64, 128, true, true, true>
        <<<dim3((N_NODES + 63) / 64, 1), 256, 0, stream>>>(xb, Wep, be, hb, h);

    // 3 GAT layers
    for (int l = 0; l < 3; ++l) {
        gemm_mh_kernel<128, 512, false, false, false>
            <<<dim3((N_NODES + 63) / 64, 4), 256, 0, stream>>>(
                hb, Wgp + (size_t)l * 65536, nullptr, xhb, nullptr);
        esed_kernel<<<N_NODES / 4, 256, 0, stream>>>(xhb, ags + l * HC, agd + l * HC, es, ed);
        gat_agg_kernel<<<N_NODES, 64, 0, stream>>>(xhb, es, ed, rowstart, csr_src,
                                                   bg + l * HID, h, hb);
    }

    // pooling (parallel, deterministic)
    pool_kernel2<<<N_GRAPHS, 1024, 0, stream>>>(h, batch, pr0b);

    // fused VAE chain: pr0 -> Wa1 -> Wa2 -> mu/lv -> z -> Wn1 -> Wn2 (one block)
    fused_vae_kernel<<<1, 256, 0, stream>>>(
        pr0b, eps, Wa1p, ba1, Wa2p, ba2, Wmulvp, bmu, blv,
        Wn1p, bn1, Wn2p, bn2, pr_o, mu_o, lv_o, z_o, zbf, g2bb);

    // nodes = sigmoid(g2 @ Wn3 + bn3) + raw bf16
    gemm64_kernel<512, 4, 2, false><<<200, 256, 0, stream>>>(
        g2bb, Wn3p, bn3, nullptr, nodep_o, nullptr, nbf, 3200);

    // fused edge + reaction MLPs
    edge_react_mfma<<<dim3(20, 64), 256, 0, stream>>>(
        zbf, nbf, piA, pjA, We1p, be1, We2p, be2, We3, be3,
        Wr1p, br1, Wr2, br2, edgep_o, react_o);
}